// Round 3
// baseline (1171.444 us; speedup 1.0000x reference)
//
#include <hip/hip_runtime.h>
#include <hip/hip_bf16.h>

#define NN 4096
#define HD 128
#define KE 32
#define KI 20
#define XLD 132  // packed-X LDS row stride in dwords

// output element offsets
#define OFF_H   0
#define OFF_POS 524288
#define OFF_F   536576
#define OFF_S   548864
#define OFF_C   794624
#define OFF_ST  1056768

typedef unsigned short u16;
typedef unsigned long long u64;
typedef __attribute__((ext_vector_type(8))) short bf16x8;   // 8 bf16 (4 VGPR)
typedef __attribute__((ext_vector_type(4))) float f32x4;

#define PERM_HI 0x07060302u  // D = [S0.hi16, S1.hi16]
#define PERM_LO 0x05040100u  // D = [S0.lo16, S1.lo16]

__device__ __forceinline__ float b2f(u16 u) {
  union { unsigned int i; float f; } c; c.i = ((unsigned int)u) << 16; return c.f;
}
__device__ __forceinline__ float silu_f(float x) { return x / (1.f + __expf(-x)); }
__device__ __forceinline__ void stout(void* out, int fp32m, size_t i, float v) {
  if (fp32m) ((float*)out)[i] = v;
  else ((__hip_bfloat16*)out)[i] = __float2bfloat16(v);
}
// RNE float->bf16 bits (scalar reference path, used in pack_weights)
__device__ __forceinline__ unsigned int f2b(float f) {
  unsigned int u = __float_as_uint(f);
  return (u + 0x7fffu + ((u >> 16) & 1u)) >> 16;
}
// pack (hi,lo) bf16 split of fp32 into one u32: hi in bytes 2-3, lo in bytes 0-1
__device__ __forceinline__ unsigned int packhl(float v) {
  unsigned int hb = f2b(v);
  float hf = __uint_as_float(hb << 16);
  unsigned int lb = f2b(v - hf);
  return (hb << 16) | lb;
}
// 2-value packhl via v_cvt_pk_bf16_f32 (RNE, same bits as f2b, half the VALU)
__device__ __forceinline__ void packhl2(float a, float b,
                                        unsigned int& pa, unsigned int& pb) {
  unsigned int H, L;
  asm("v_cvt_pk_bf16_f32 %0, %1, %2" : "=v"(H) : "v"(a), "v"(b));
  float hfa = __uint_as_float(H << 16);
  float hfb = __uint_as_float(H & 0xffff0000u);
  asm("v_cvt_pk_bf16_f32 %0, %1, %2" : "=v"(L) : "v"(a - hfa), "v"(b - hfb));
  pa = __builtin_amdgcn_perm(H, L, PERM_LO);  // [bf16(a) : bf16(a-hi)]
  pb = __builtin_amdgcn_perm(H, L, PERM_HI);  // [bf16(b) : bf16(b-hi)]
}
__device__ __forceinline__ bf16x8 mk8(unsigned int a, unsigned int b,
                                      unsigned int c, unsigned int d) {
  union { unsigned int u[4]; bf16x8 v; } t;
  t.u[0] = a; t.u[1] = b; t.u[2] = c; t.u[3] = d; return t.v;
}

// ---------------- dtype probe: are float inputs fp32 or bf16? ----------------
__global__ void probe_dtype(const u16* __restrict__ h, int* __restrict__ flag) {
  if (threadIdx.x == 0) atomicExch(flag, 0);
  __syncthreads();
  int bad = 0;
  for (int i = threadIdx.x; i < 8192; i += 256) {
    float v = b2f(h[i]);
    if (!(v > -1000.f && v < 1000.f)) bad = 1;
  }
  if (bad) atomicOr(flag, 1);
}

// ---------------- convert all float tensors -> fp32 workspace ----------------
struct CvtTable {
  const void* src[25];
  int dstoff[25];
  int cnt[25];
};

__global__ void convert_all(CvtTable tab, float* __restrict__ wsf, const int* __restrict__ flag) {
  const int seg = blockIdx.y;
  const int i = blockIdx.x * 256 + threadIdx.x;
  if (i >= tab.cnt[seg]) return;
  float v;
  if (*flag) v = ((const float*)tab.src[seg])[i];
  else       v = b2f(((const u16*)tab.src[seg])[i]);
  wsf[tab.dstoff[seg] + i] = v;
}

// ---------------- pack stage weights into MFMA B-fragment order --------------
// B-frag layout for mfma_f32_16x16x32_bf16: lane l holds B[k][col] with
// col = l&15, k = (l>>4)*8 + j, j=0..7 contiguous -> one dwordx4 per frag.
// Output: [mat 18][kt 4][ot 8][lane 64][j 8] bf16, separate hi and lo arrays.
__global__ void pack_weights(const float* __restrict__ wsf, int offEW1, int offEW2, int offCW1,
                             u16* __restrict__ WBH, u16* __restrict__ WBL) {
  int tid = blockIdx.x * 256 + threadIdx.x;
  if (tid >= 18 * 16384) return;
  int m = tid >> 14;
  int rix = tid & 16383;
  int layer = m / 3, s = m % 3;
  const float* src;
  if (s == 0)      src = wsf + offEW1 + (size_t)layer * 257 * HD + 128 * HD;
  else if (s == 1) src = wsf + offEW2 + (size_t)layer * HD * HD;
  else             src = wsf + offCW1 + (size_t)layer * HD * HD;
  int j = rix & 7, lane = (rix >> 3) & 63, ot = (rix >> 9) & 7, kt = rix >> 12;
  int f = kt * 32 + (lane >> 4) * 8 + j;
  int o = ot * 16 + (lane & 15);
  float v = src[f * HD + o];
  unsigned int hb = f2b(v);
  float hf = __uint_as_float(hb << 16);
  unsigned int lb = f2b(v - hf);
  WBH[tid] = (u16)hb;
  WBL[tid] = (u16)lb;
}

// ---------------- graph boundaries from sorted batch ----------------
__global__ void graph_bounds(const int* __restrict__ batch, int* __restrict__ gstart) {
  int n = blockIdx.x * 256 + threadIdx.x;
  if (n >= NN) return;
  int v = batch[n];
  int pv = (n == 0) ? -1 : batch[n - 1];
  for (int b = pv + 1; b <= v; b++) gstart[b] = n;
  if (n == NN - 1) for (int b = v + 1; b <= 32; b++) gstart[b] = NN;
}

// ---------------- exact k-NN within cutoff (one wave per node) ----------------
__global__ __launch_bounds__(256) void neigh_kernel(
    const float* __restrict__ pos, const int* __restrict__ batch,
    const int* __restrict__ gstart, int* __restrict__ idx, int* __restrict__ cnt,
    int Ksel, float cut2) {
  const int lane = threadIdx.x & 63;
  const int i = blockIdx.x * 4 + (threadIdx.x >> 6);
  const int b = batch[i];
  const int gs = gstart[b];
  const int ge = gstart[b + 1];
  const int span = ge - gs;
  const float px = pos[i * 3 + 0], py = pos[i * 3 + 1], pz = pos[i * 3 + 2];
  u64 key[16];
#pragma unroll
  for (int tq = 0; tq < 16; tq++) {
    u64 k64 = ~0ull;
    if (tq * 64 < span) {
      int j = gs + tq * 64 + lane;
      if (j < ge && j != i) {
        float dx = px - pos[j * 3 + 0];
        float dy = py - pos[j * 3 + 1];
        float dz = pz - pos[j * 3 + 2];
        float d2 = dx * dx + dy * dy + dz * dz;
        if (d2 <= cut2) k64 = (((u64)__float_as_uint(d2)) << 32) | (unsigned int)j;
      }
    }
    key[tq] = k64;
  }
  u64 thresh = 0;
  int myidx = i;
  int mycnt = 0;
  for (int s = 0; s < Ksel; s++) {
    u64 m = ~0ull;
#pragma unroll
    for (int tq = 0; tq < 16; tq++) {
      if (tq * 64 < span) {
        u64 kk = key[tq];
        if (kk >= thresh && kk < m) m = kk;
      }
    }
    for (int off = 32; off > 0; off >>= 1) {
      u64 o = __shfl_down(m, (unsigned)off, 64);
      if (o < m) m = o;
    }
    m = __shfl(m, 0, 64);
    if (m != ~0ull) {
      if (lane == s) myidx = (int)(m & 0xffffffffu);
      mycnt++;
      thresh = m + 1;
    } else break;
  }
  if (lane < Ksel) idx[i * Ksel + lane] = myidx;
  if (lane == 0) cnt[i] = mycnt;
}

// 3-term split-bf16 MFMA stage: OUT[e][o] = sum_f X[e][f]*W[f][o] computed as
// Xhi*Whi + Xhi*Wlo + Xlo*Whi in fp32 accumulators (rel err ~2^-17).
__device__ __forceinline__ void mfma_stage(const unsigned int* xin,
                                           const u16* __restrict__ WH,
                                           const u16* __restrict__ WL,
                                           int E, int ob, int lane, f32x4 acc[4]) {
  const int l16 = lane & 15, q = lane >> 4;
  const unsigned int* xr = xin + (E * 16 + l16) * XLD + q * 8;
  f32x4 z = {0.f, 0.f, 0.f, 0.f};
  acc[0] = z; acc[1] = z; acc[2] = z; acc[3] = z;
#pragma unroll
  for (int kt = 0; kt < 4; kt++) {
    uint4 xa = *(const uint4*)(xr + kt * 32);
    uint4 xb = *(const uint4*)(xr + kt * 32 + 4);
    bf16x8 ah = mk8(__builtin_amdgcn_perm(xa.y, xa.x, PERM_HI),
                    __builtin_amdgcn_perm(xa.w, xa.z, PERM_HI),
                    __builtin_amdgcn_perm(xb.y, xb.x, PERM_HI),
                    __builtin_amdgcn_perm(xb.w, xb.z, PERM_HI));
    bf16x8 al = mk8(__builtin_amdgcn_perm(xa.y, xa.x, PERM_LO),
                    __builtin_amdgcn_perm(xa.w, xa.z, PERM_LO),
                    __builtin_amdgcn_perm(xb.y, xb.x, PERM_LO),
                    __builtin_amdgcn_perm(xb.w, xb.z, PERM_LO));
#pragma unroll
    for (int ot = 0; ot < 4; ot++) {
      const int off = ((kt * 8 + ob + ot) * 64 + lane) * 8;
      bf16x8 wh = *(const bf16x8*)(WH + off);
      bf16x8 wl = *(const bf16x8*)(WL + off);
      acc[ot] = __builtin_amdgcn_mfma_f32_16x16x32_bf16(al, wh, acc[ot], 0, 0, 0);
      acc[ot] = __builtin_amdgcn_mfma_f32_16x16x32_bf16(ah, wl, acc[ot], 0, 0, 0);
      acc[ot] = __builtin_amdgcn_mfma_f32_16x16x32_bf16(ah, wh, acc[ot], 0, 0, 0);
    }
  }
}

// ---------------- one EGNN layer, one block per 2 nodes ----------------
// Single in-place X buffer: every MFMA stage reads all columns of its rows
// BEFORE any wave writes outputs (read phase | barrier | write phase), so the
// m1/m2 outputs can overwrite hj/m1 in place. LDS 78KB -> 44.5KB => 3 blk/CU.
__global__ __launch_bounds__(512, 6) void egnn_layer(
    const float* __restrict__ h_in, const float* __restrict__ pos_in,
    float* __restrict__ h_out, float* __restrict__ pos_out,
    const int* __restrict__ idx, const int* __restrict__ cnt,
    const float* __restrict__ ew1, const float* __restrict__ eb1,
    const float* __restrict__ eb2,
    const float* __restrict__ cb1, const float* __restrict__ cw2,
    const float* __restrict__ nw1, const float* __restrict__ nb1,
    const float* __restrict__ nw2, const float* __restrict__ nb2,
    const u16* __restrict__ wbh, const u16* __restrict__ wbl) {
  __shared__ __align__(16) unsigned int xp[64 * XLD];  // packed hi|lo X, [e][f]
  __shared__ float hi_s[2][HD], hpart_s[2][HD], msum_s[2][HD], u_s[2][HD];
  __shared__ float red_s[512];
  __shared__ float msum_red[4][HD];   // per-e-tile partial msum
  __shared__ float ce_red[64][2];     // per-e partial c-dot (o halves)
  __shared__ float rel_s[3][64], d2_s[64], mf_s[64], ce_s[64];
  __shared__ int idx_s[64], cn_s[2];

  const int t = threadIdx.x;
  const int i0 = blockIdx.x * 2;
  const int e = t & 63;
  const int lane = t & 63;
  const int wid8 = __builtin_amdgcn_readfirstlane(t >> 6);  // 0..7
  const int E = wid8 & 3;            // e-tile (16 edges)
  const int ob = (wid8 >> 2) * 4;    // first o-tile (4 tiles = 64 outputs)
  const int l16 = lane & 15, q = lane >> 4;

  if (t < 64) idx_s[t] = idx[(size_t)(i0 + (t >> 5)) * KE + (t & 31)];
  else if (t < 66) cn_s[t - 64] = cnt[i0 + (t - 64)];
  if (t >= 256) {
    const int nt = t - 256;
    hi_s[nt >> 7][nt & 127] = h_in[(size_t)(i0 + (nt >> 7)) * HD + (nt & 127)];
  }
  __syncthreads();

  if (t < 64) {
    const int nd = t >> 5, ic = i0 + nd;
    const int j = idx_s[t];
    const float rx = pos_in[ic * 3 + 0] - pos_in[j * 3 + 0];
    const float ry = pos_in[ic * 3 + 1] - pos_in[j * 3 + 1];
    const float rz = pos_in[ic * 3 + 2] - pos_in[j * 3 + 2];
    rel_s[0][t] = rx; rel_s[1][t] = ry; rel_s[2][t] = rz;
    d2_s[t] = rx * rx + ry * ry + rz * rz;
    mf_s[t] = ((t & 31) < cn_s[nd]) ? 1.0f : 0.0f;
  }
  // gather hj -> xp[e][f] packed hi|lo (wave stages a 16-f slab for its cols)
  {
    const int j = idx_s[e];
    const int f0 = (t >> 6) * 16;
    const float4* src = (const float4*)(h_in + (size_t)j * HD + f0);
    unsigned int* dst = xp + e * XLD + f0;
#pragma unroll
    for (int qq = 0; qq < 4; qq++) {
      float4 v = src[qq];
      unsigned int p0, p1, p2, p3;
      packhl2(v.x, v.y, p0, p1);
      packhl2(v.z, v.w, p2, p3);
      dst[qq * 4 + 0] = p0;
      dst[qq * 4 + 1] = p1;
      dst[qq * 4 + 2] = p2;
      dst[qq * 4 + 3] = p3;
    }
  }
  // hpart[nd][o] = hi . ew1[0:128, o]  (edge-invariant half of edge MLP1)
  {
    const int oo = t & 127, nd = (t >> 7) & 1, hf = t >> 8;
    const float* hsrc = hi_s[nd];
    float hp = 0.f;
#pragma unroll
    for (int f4 = hf * 16; f4 < hf * 16 + 16; f4++) {
      float4 xv = *(const float4*)(hsrc + f4 * 4);
      hp = fmaf(xv.x, ew1[(f4 * 4 + 0) * HD + oo], hp);
      hp = fmaf(xv.y, ew1[(f4 * 4 + 1) * HD + oo], hp);
      hp = fmaf(xv.z, ew1[(f4 * 4 + 2) * HD + oo], hp);
      hp = fmaf(xv.w, ew1[(f4 * 4 + 3) * HD + oo], hp);
    }
    red_s[t] = hp;
  }
  __syncthreads();
  if (t < 256) hpart_s[t >> 7][t & 127] = red_s[t] + red_s[t + 256] + eb1[t & 127];
  __syncthreads();

  // ---- stage B: m1 = silu(hpart + hj @ ew1[128:256] + d2*ew1[256]) ----
  {
    f32x4 acc[4];
    mfma_stage(xp, wbh, wbl, E, ob, lane, acc);
    __syncthreads();  // all xp reads done before in-place overwrite
    const int nd = E >> 1;
    float d2v[4];
#pragma unroll
    for (int r = 0; r < 4; r++) d2v[r] = d2_s[E * 16 + q * 4 + r];
#pragma unroll
    for (int ot = 0; ot < 4; ot++) {
      const int o = (ob + ot) * 16 + l16;
      const float hp = hpart_s[nd][o];
      const float w2 = ew1[256 * HD + o];
      float s0 = silu_f(acc[ot][0] + hp + d2v[0] * w2);
      float s1 = silu_f(acc[ot][1] + hp + d2v[1] * w2);
      float s2 = silu_f(acc[ot][2] + hp + d2v[2] * w2);
      float s3 = silu_f(acc[ot][3] + hp + d2v[3] * w2);
      unsigned int p0, p1, p2, p3;
      packhl2(s0, s1, p0, p1);
      packhl2(s2, s3, p2, p3);
      const int eb_ = E * 16 + q * 4;
      xp[(eb_ + 0) * XLD + o] = p0;
      xp[(eb_ + 1) * XLD + o] = p1;
      xp[(eb_ + 2) * XLD + o] = p2;
      xp[(eb_ + 3) * XLD + o] = p3;
    }
  }
  __syncthreads();

  // ---- stage C: m2 = mask ? silu(m1 @ ew2 + eb2) : 0 ; msum partials ----
  {
    f32x4 acc[4];
    mfma_stage(xp, wbh + 16384, wbl + 16384, E, ob, lane, acc);
    __syncthreads();  // all xp reads done before in-place overwrite
    float mfv[4];
#pragma unroll
    for (int r = 0; r < 4; r++) mfv[r] = mf_s[E * 16 + q * 4 + r];
    float msp[4] = {0.f, 0.f, 0.f, 0.f};
#pragma unroll
    for (int ot = 0; ot < 4; ot++) {
      const int o = (ob + ot) * 16 + l16;
      const float bb = eb2[o];
      float mm[4];
#pragma unroll
      for (int r = 0; r < 4; r++) {
        mm[r] = (mfv[r] != 0.f) ? silu_f(acc[ot][r] + bb) : 0.f;
        msp[ot] += mm[r];
      }
      unsigned int p0, p1, p2, p3;
      packhl2(mm[0], mm[1], p0, p1);
      packhl2(mm[2], mm[3], p2, p3);
      const int eb_ = E * 16 + q * 4;
      xp[(eb_ + 0) * XLD + o] = p0;
      xp[(eb_ + 1) * XLD + o] = p1;
      xp[(eb_ + 2) * XLD + o] = p2;
      xp[(eb_ + 3) * XLD + o] = p3;
    }
    // reduce msum over the 4 q-groups (e within tile); write per-tile partial
#pragma unroll
    for (int ot = 0; ot < 4; ot++) {
      float s = msp[ot];
      s += __shfl_xor(s, 16);
      s += __shfl_xor(s, 32);
      msp[ot] = s;
    }
    if (lane < 16) {
#pragma unroll
      for (int ot = 0; ot < 4; ot++) msum_red[E][(ob + ot) * 16 + lane] = msp[ot];
    }
  }
  __syncthreads();

  // ---- stage D: c1 = silu(m2 @ cw1 + cb1); fold cw2 dot in-register ----
  {
    f32x4 acc[4];
    mfma_stage(xp, wbh + 32768, wbl + 32768, E, ob, lane, acc);
    float cp[4] = {0.f, 0.f, 0.f, 0.f};
#pragma unroll
    for (int ot = 0; ot < 4; ot++) {
      const int o = (ob + ot) * 16 + l16;
      const float b1 = cb1[o];
      const float c2 = cw2[o];
#pragma unroll
      for (int r = 0; r < 4; r++)
        cp[r] = fmaf(silu_f(acc[ot][r] + b1), c2, cp[r]);
    }
#pragma unroll
    for (int r = 0; r < 4; r++) {
      float s = cp[r];
      s += __shfl_xor(s, 1);
      s += __shfl_xor(s, 2);
      s += __shfl_xor(s, 4);
      s += __shfl_xor(s, 8);
      cp[r] = s;
    }
    if (l16 == 0) {
#pragma unroll
      for (int r = 0; r < 4; r++) ce_red[E * 16 + q * 4 + r][ob >> 2] = cp[r];
    }
  }
  __syncthreads();
  if (t < 64) ce_s[t] = (mf_s[t] != 0.f) ? (ce_red[t][0] + ce_red[t][1]) : 0.f;
  if (t < 256) {
    const int nd = t >> 7, oo = t & 127;
    msum_s[nd][oo] = msum_red[nd * 2][oo] + msum_red[nd * 2 + 1][oo];
  }
  __syncthreads();
  // ---- pos update ----
  if (t < 6) {
    const int nd = t / 3, ax = t - nd * 3, ic = i0 + nd;
    float s = 0.f;
#pragma unroll
    for (int k = 0; k < 32; k++) s = fmaf(rel_s[ax][nd * 32 + k], ce_s[nd * 32 + k], s);
    const float cntf = fmaxf((float)cn_s[nd], 1.f);
    pos_out[ic * 3 + ax] = pos_in[ic * 3 + ax] + s / cntf;
  }
  // ---- node MLP1 ----
  {
    const int oo = t & 127, nd = (t >> 7) & 1, ph = t >> 8;
    const float* src = ph ? msum_s[nd] : hi_s[nd];
    const float* Wp = nw1 + (size_t)ph * 128 * HD + oo;
    float p = 0.f;
#pragma unroll
    for (int f4 = 0; f4 < 32; f4++) {
      float4 xv = *(const float4*)(src + f4 * 4);
      p = fmaf(xv.x, Wp[(f4 * 4 + 0) * HD], p);
      p = fmaf(xv.y, Wp[(f4 * 4 + 1) * HD], p);
      p = fmaf(xv.z, Wp[(f4 * 4 + 2) * HD], p);
      p = fmaf(xv.w, Wp[(f4 * 4 + 3) * HD], p);
    }
    red_s[t] = p;
  }
  __syncthreads();
  if (t < 256) u_s[t >> 7][t & 127] = silu_f(red_s[t] + red_s[t + 256] + nb1[t & 127]);
  __syncthreads();
  // ---- node MLP2 + residual ----
  {
    const int oo = t & 127, nd = (t >> 7) & 1, ph = t >> 8;
    const float* src = u_s[nd] + ph * 64;
    const float* Wp = nw2 + (size_t)ph * 64 * HD + oo;
    float p = 0.f;
#pragma unroll
    for (int f4 = 0; f4 < 16; f4++) {
      float4 xv = *(const float4*)(src + f4 * 4);
      p = fmaf(xv.x, Wp[(f4 * 4 + 0) * HD], p);
      p = fmaf(xv.y, Wp[(f4 * 4 + 1) * HD], p);
      p = fmaf(xv.z, Wp[(f4 * 4 + 2) * HD], p);
      p = fmaf(xv.w, Wp[(f4 * 4 + 3) * HD], p);
    }
    red_s[t] = p;
  }
  __syncthreads();
  if (t < 256) {
    const int nd = t >> 7, oo = t & 127;
    h_out[(size_t)(i0 + nd) * HD + oo] = hi_s[nd][oo] + red_s[t] + red_s[t + 256] + nb2[oo];
  }
}

// ---------------- final heads (per node) ----------------
__global__ __launch_bounds__(256) void heads_kernel(
    const float* __restrict__ h, const float* __restrict__ pos,
    const float* __restrict__ fw1, const float* __restrict__ fb1,
    const float* __restrict__ fw2, const float* __restrict__ fb2,
    const float* __restrict__ cw1g, const float* __restrict__ cb1g,
    const float* __restrict__ cw2g, const float* __restrict__ cb2g,
    const float* __restrict__ sw, const float* __restrict__ sb,
    const float* __restrict__ iw,
    float* __restrict__ At, float* __restrict__ Bt,
    void* __restrict__ out, const int* __restrict__ flag) {
  __shared__ float hi_s[HD], v1[HD], red_s[256];
  const int i = blockIdx.x, t = threadIdx.x;
  const int fm = *flag;
  if (t < HD) hi_s[t] = h[(size_t)i * HD + t];
  __syncthreads();
  const int o = t & 127, ph = t >> 7;
  // forces MLP1
  {
    float p = 0.f;
#pragma unroll 4
    for (int f = ph * 64; f < ph * 64 + 64; f++) p = fmaf(hi_s[f], fw1[f * HD + o], p);
    red_s[t] = p;
  }
  __syncthreads();
  if (t < HD) v1[t] = tanhf(red_s[t] + red_s[t + 128] + fb1[t]);
  __syncthreads();
  if (t < 3) {
    float p = 0.f;
    for (int f = 0; f < HD; f++) p = fmaf(v1[f], fw2[f * 3 + t], p);
    stout(out, fm, OFF_F + (size_t)i * 3 + t, p + fb2[t]);
  }
  __syncthreads();
  // conformer MLP1
  {
    float p = 0.f;
#pragma unroll 4
    for (int f = ph * 64; f < ph * 64 + 64; f++) p = fmaf(hi_s[f], cw1g[f * HD + o], p);
    red_s[t] = p;
  }
  __syncthreads();
  if (t < HD) v1[t] = fmaxf(red_s[t] + red_s[t + 128] + cb1g[t], 0.f);
  __syncthreads();
  // conformer MLP2
  {
    const int oo = t & 63, pc = t >> 6;
    float p = 0.f;
#pragma unroll 4
    for (int f = pc * 32; f < pc * 32 + 32; f++) p = fmaf(v1[f], cw2g[f * 64 + oo], p);
    red_s[t] = p;
  }
  __syncthreads();
  if (t < 64)
    stout(out, fm, OFF_C + (size_t)i * 64 + t,
          red_s[t] + red_s[t + 64] + red_s[t + 128] + red_s[t + 192] + cb2g[t]);
  __syncthreads();
  // steric
  if (t < HD) red_s[t] = hi_s[t] * sw[t];
  __syncthreads();
  if (t == 0) {
    float p = 0.f;
    for (int f = 0; f < HD; f++) p += red_s[f];
    stout(out, fm, OFF_ST + (size_t)i, p + sb[0]);
  }
  __syncthreads();
  // interaction head per-node dots
  {
    const int g = t >> 5, l = t & 31;
    float p = 0.f;
    if (g < 6) {
      const int tt = g >> 1, half = g & 1;
#pragma unroll
      for (int r2 = 0; r2 < 4; r2++)
        p = fmaf(hi_s[l * 4 + r2], iw[tt * 258 + half * 128 + l * 4 + r2], p);
    }
    red_s[t] = p;
  }
  __syncthreads();
  if (t < 6) {
    float p = 0.f;
    for (int l = 0; l < 32; l++) p += red_s[t * 32 + l];
    const int tt = t >> 1;
    if ((t & 1) == 0) At[tt * NN + i] = p;
    else Bt[tt * NN + i] = p;
  }
  if (t < HD) stout(out, fm, OFF_H + (size_t)i * HD + t, hi_s[t]);
  if (t >= 128 && t < 131) stout(out, fm, OFF_POS + (size_t)i * 3 + (t - 128), pos[i * 3 + (t - 128)]);
}

// ---------------- interaction scores ----------------
__global__ void scores_kernel(const float* __restrict__ pos, const int* __restrict__ idx2,
                              const int* __restrict__ cnt2, const float* __restrict__ At,
                              const float* __restrict__ Bt, const float* __restrict__ iw,
                              const float* __restrict__ ib, void* __restrict__ out,
                              const int* __restrict__ flag) {
  int tid = blockIdx.x * 256 + threadIdx.x;
  if (tid >= 3 * NN * KI) return;
  const int fm = *flag;
  const int tt = tid / (NN * KI);
  const int r = tid % (NN * KI);
  const int n = r / KI;
  const int k = r % KI;
  float v = 0.f;
  if (k < cnt2[n]) {
    int j = idx2[n * KI + k];
    float dx = pos[n * 3 + 0] - pos[j * 3 + 0];
    float dy = pos[n * 3 + 1] - pos[j * 3 + 1];
    float dz = pos[n * 3 + 2] - pos[j * 3 + 2];
    float d2 = dx * dx + dy * dy + dz * dz;
    float dist = sqrtf(d2 + 1e-12f);
    float s = At[tt * NN + n] + Bt[tt * NN + j] + dist * iw[tt * 258 + 256] +
              (dist * 0.1f) * iw[tt * 258 + 257] + ib[tt];
    v = 1.f / (1.f + __expf(-s));
  }
  stout(out, fm, OFF_S + (size_t)tid, v);
}

extern "C" void kernel_launch(void* const* d_in, const int* in_sizes, int n_in,
                              void* d_out, int out_size, void* d_ws, size_t ws_size,
                              hipStream_t stream) {
  (void)in_sizes; (void)n_in; (void)out_size; (void)ws_size;

  float* wsf = (float*)d_ws;
  float* h_a = wsf + 0;             // 524288
  float* pos_a = wsf + 524288;      // 12288
  float* h_b = wsf + 536576;        // 524288
  float* pos_b = wsf + 1060864;     // 12288
  float* At = wsf + 1073152;        // 12288
  float* Bt = wsf + 1085440;        // 12288
  const int W0 = 1097728;

  static const int wcnt[23] = {197376, 768, 98304, 768, 98304, 768, 768,
                               196608, 768, 98304, 768, 16384, 128, 384, 3,
                               774, 3, 16384, 128, 8192, 64, 128, 1};
  int woff[23];
  {
    int o = W0;
    for (int k = 0; k < 23; k++) { woff[k] = o; o += wcnt[k]; }
  }
  const int IOFF = woff[22] + wcnt[22];
  int* ibase = (int*)d_ws;
  int* idx1 = ibase + IOFF;
  int* cnt1 = idx1 + NN * KE;
  int* idx2 = cnt1 + NN;
  int* cnt2 = idx2 + NN * KI;
  int* gstart = cnt2 + NN;
  int* flag = gstart + 33;
  // packed MFMA weight fragments (bf16 hi/lo), 16B-aligned
  int wboff = (int)((flag + 1) - ibase);
  wboff = (wboff + 3) & ~3;
  u16* WBH = (u16*)(ibase + wboff);
  u16* WBL = WBH + 18 * 16384;

  const float* EW1 = wsf + woff[0];
  const float* EB1 = wsf + woff[1];
  const float* EB2 = wsf + woff[3];
  const float* CB1 = wsf + woff[5];
  const float* CW2 = wsf + woff[6];
  const float* NW1 = wsf + woff[7];
  const float* NB1 = wsf + woff[8];
  const float* NW2 = wsf + woff[9];
  const float* NB2 = wsf + woff[10];
  const float* FW1 = wsf + woff[11];
  const float* FB1 = wsf + woff[12];
  const float* FW2 = wsf + woff[13];
  const float* FB2 = wsf + woff[14];
  const float* IW = wsf + woff[15];
  const float* IB = wsf + woff[16];
  const float* CW1G = wsf + woff[17];
  const float* CB1G = wsf + woff[18];
  const float* CW2G = wsf + woff[19];
  const float* CB2G = wsf + woff[20];
  const float* SW = wsf + woff[21];
  const float* SB = wsf + woff[22];

  probe_dtype<<<1, 256, 0, stream>>>((const u16*)d_in[0], flag);

  CvtTable tab;
  tab.src[0] = d_in[0]; tab.dstoff[0] = 0;       tab.cnt[0] = NN * HD;
  tab.src[1] = d_in[1]; tab.dstoff[1] = 524288;  tab.cnt[1] = NN * 3;
  for (int k = 0; k < 23; k++) {
    tab.src[2 + k] = d_in[3 + k];
    tab.dstoff[2 + k] = woff[k];
    tab.cnt[2 + k] = wcnt[k];
  }
  {
    dim3 g((NN * HD + 255) / 256, 25, 1);
    convert_all<<<g, 256, 0, stream>>>(tab, wsf, flag);
  }
  pack_weights<<<(18 * 16384 + 255) / 256, 256, 0, stream>>>(
      wsf, woff[0], woff[2], woff[4], WBH, WBL);

  const int* batch = (const int*)d_in[2];
  graph_bounds<<<NN / 256, 256, 0, stream>>>(batch, gstart);

  const float cut2s[3] = {9.f, 36.f, 100.f};
  float *hin = h_a, *pin = pos_a, *hout = h_b, *pout = pos_b;
  for (int l = 0; l < 6; l++) {
    if ((l & 1) == 0)
      neigh_kernel<<<NN / 4, 256, 0, stream>>>(pin, batch, gstart, idx1, cnt1, KE, cut2s[l >> 1]);
    egnn_layer<<<NN / 2, 512, 0, stream>>>(
        hin, pin, hout, pout, idx1, cnt1,
        EW1 + (size_t)l * 257 * HD, EB1 + (size_t)l * HD,
        EB2 + (size_t)l * HD,
        CB1 + (size_t)l * HD, CW2 + (size_t)l * HD,
        NW1 + (size_t)l * 256 * HD, NB1 + (size_t)l * HD,
        NW2 + (size_t)l * HD * HD, NB2 + (size_t)l * HD,
        WBH + (size_t)l * 3 * 16384, WBL + (size_t)l * 3 * 16384);
    float* th = hin; hin = hout; hout = th;
    float* tp = pin; pin = pout; pout = tp;
  }
  neigh_kernel<<<NN / 4, 256, 0, stream>>>(pin, batch, gstart, idx2, cnt2, KI, 100.f);
  heads_kernel<<<NN, 256, 0, stream>>>(hin, pin, FW1, FB1, FW2, FB2, CW1G, CB1G, CW2G, CB2G,
                                       SW, SB, IW, At, Bt, d_out, flag);
  scores_kernel<<<(3 * NN * KI + 255) / 256, 256, 0, stream>>>(
      pin, idx2, cnt2, At, Bt, IW, IB, d_out, flag);
}

// Round 4
// 945.940 us; speedup vs baseline: 1.2384x; 1.2384x over previous
//
#include <hip/hip_runtime.h>
#include <hip/hip_bf16.h>

#define NN 4096
#define HD 128
#define KE 32
#define KI 20
#define XLD 132  // packed-X LDS row stride in dwords

// output element offsets
#define OFF_H   0
#define OFF_POS 524288
#define OFF_F   536576
#define OFF_S   548864
#define OFF_C   794624
#define OFF_ST  1056768

typedef unsigned short u16;
typedef unsigned long long u64;
typedef __attribute__((ext_vector_type(8))) short bf16x8;   // 8 bf16 (4 VGPR)
typedef __attribute__((ext_vector_type(4))) float f32x4;

#define PERM_HI 0x07060302u  // D = [S0.hi16, S1.hi16]
#define PERM_LO 0x05040100u  // D = [S0.lo16, S1.lo16]

__device__ __forceinline__ float b2f(u16 u) {
  union { unsigned int i; float f; } c; c.i = ((unsigned int)u) << 16; return c.f;
}
__device__ __forceinline__ float silu_f(float x) { return x / (1.f + __expf(-x)); }
__device__ __forceinline__ void stout(void* out, int fp32m, size_t i, float v) {
  if (fp32m) ((float*)out)[i] = v;
  else ((__hip_bfloat16*)out)[i] = __float2bfloat16(v);
}
// RNE float->bf16 bits (scalar reference path, used in pack_weights)
__device__ __forceinline__ unsigned int f2b(float f) {
  unsigned int u = __float_as_uint(f);
  return (u + 0x7fffu + ((u >> 16) & 1u)) >> 16;
}
// 2-value packhl via v_cvt_pk_bf16_f32 (RNE, same bits as f2b, half the VALU)
__device__ __forceinline__ void packhl2(float a, float b,
                                        unsigned int& pa, unsigned int& pb) {
  unsigned int H, L;
  asm("v_cvt_pk_bf16_f32 %0, %1, %2" : "=v"(H) : "v"(a), "v"(b));
  float hfa = __uint_as_float(H << 16);
  float hfb = __uint_as_float(H & 0xffff0000u);
  asm("v_cvt_pk_bf16_f32 %0, %1, %2" : "=v"(L) : "v"(a - hfa), "v"(b - hfb));
  pa = __builtin_amdgcn_perm(H, L, PERM_LO);  // [bf16(a) : bf16(a-hi)]
  pb = __builtin_amdgcn_perm(H, L, PERM_HI);  // [bf16(b) : bf16(b-hi)]
}
__device__ __forceinline__ bf16x8 mk8(unsigned int a, unsigned int b,
                                      unsigned int c, unsigned int d) {
  union { unsigned int u[4]; bf16x8 v; } t;
  t.u[0] = a; t.u[1] = b; t.u[2] = c; t.u[3] = d; return t.v;
}

// ---------------- dtype probe: are float inputs fp32 or bf16? ----------------
__global__ void probe_dtype(const u16* __restrict__ h, int* __restrict__ flag) {
  if (threadIdx.x == 0) atomicExch(flag, 0);
  __syncthreads();
  int bad = 0;
  for (int i = threadIdx.x; i < 8192; i += 256) {
    float v = b2f(h[i]);
    if (!(v > -1000.f && v < 1000.f)) bad = 1;
  }
  if (bad) atomicOr(flag, 1);
}

// ---------------- convert all float tensors -> fp32 workspace ----------------
struct CvtTable {
  const void* src[25];
  int dstoff[25];
  int cnt[25];
};

__global__ void convert_all(CvtTable tab, float* __restrict__ wsf, const int* __restrict__ flag) {
  const int seg = blockIdx.y;
  const int i = blockIdx.x * 256 + threadIdx.x;
  if (i >= tab.cnt[seg]) return;
  float v;
  if (*flag) v = ((const float*)tab.src[seg])[i];
  else       v = b2f(((const u16*)tab.src[seg])[i]);
  wsf[tab.dstoff[seg] + i] = v;
}

// ---------------- pack stage weights into MFMA B-fragment order --------------
// B-frag layout for mfma_f32_16x16x32_bf16: lane l holds B[k][col] with
// col = l&15, k = (l>>4)*8 + j, j=0..7 contiguous -> one dwordx4 per frag.
// Output: [mat 18][kt 4][ot 8][lane 64][j 8] bf16, separate hi and lo arrays.
__global__ void pack_weights(const float* __restrict__ wsf, int offEW1, int offEW2, int offCW1,
                             u16* __restrict__ WBH, u16* __restrict__ WBL) {
  int tid = blockIdx.x * 256 + threadIdx.x;
  if (tid >= 18 * 16384) return;
  int m = tid >> 14;
  int rix = tid & 16383;
  int layer = m / 3, s = m % 3;
  const float* src;
  if (s == 0)      src = wsf + offEW1 + (size_t)layer * 257 * HD + 128 * HD;
  else if (s == 1) src = wsf + offEW2 + (size_t)layer * HD * HD;
  else             src = wsf + offCW1 + (size_t)layer * HD * HD;
  int j = rix & 7, lane = (rix >> 3) & 63, ot = (rix >> 9) & 7, kt = rix >> 12;
  int f = kt * 32 + (lane >> 4) * 8 + j;
  int o = ot * 16 + (lane & 15);
  float v = src[f * HD + o];
  unsigned int hb = f2b(v);
  float hf = __uint_as_float(hb << 16);
  unsigned int lb = f2b(v - hf);
  WBH[tid] = (u16)hb;
  WBL[tid] = (u16)lb;
}

// ---------------- graph boundaries from sorted batch ----------------
__global__ void graph_bounds(const int* __restrict__ batch, int* __restrict__ gstart) {
  int n = blockIdx.x * 256 + threadIdx.x;
  if (n >= NN) return;
  int v = batch[n];
  int pv = (n == 0) ? -1 : batch[n - 1];
  for (int b = pv + 1; b <= v; b++) gstart[b] = n;
  if (n == NN - 1) for (int b = v + 1; b <= 32; b++) gstart[b] = NN;
}

// ---------------- exact k-NN within cutoff (one wave per node) ----------------
__global__ __launch_bounds__(256) void neigh_kernel(
    const float* __restrict__ pos, const int* __restrict__ batch,
    const int* __restrict__ gstart, int* __restrict__ idx, int* __restrict__ cnt,
    int Ksel, float cut2) {
  const int lane = threadIdx.x & 63;
  const int i = blockIdx.x * 4 + (threadIdx.x >> 6);
  const int b = batch[i];
  const int gs = gstart[b];
  const int ge = gstart[b + 1];
  const int span = ge - gs;
  const float px = pos[i * 3 + 0], py = pos[i * 3 + 1], pz = pos[i * 3 + 2];
  u64 key[16];
#pragma unroll
  for (int tq = 0; tq < 16; tq++) {
    u64 k64 = ~0ull;
    if (tq * 64 < span) {
      int j = gs + tq * 64 + lane;
      if (j < ge && j != i) {
        float dx = px - pos[j * 3 + 0];
        float dy = py - pos[j * 3 + 1];
        float dz = pz - pos[j * 3 + 2];
        float d2 = dx * dx + dy * dy + dz * dz;
        if (d2 <= cut2) k64 = (((u64)__float_as_uint(d2)) << 32) | (unsigned int)j;
      }
    }
    key[tq] = k64;
  }
  u64 thresh = 0;
  int myidx = i;
  int mycnt = 0;
  for (int s = 0; s < Ksel; s++) {
    u64 m = ~0ull;
#pragma unroll
    for (int tq = 0; tq < 16; tq++) {
      if (tq * 64 < span) {
        u64 kk = key[tq];
        if (kk >= thresh && kk < m) m = kk;
      }
    }
    for (int off = 32; off > 0; off >>= 1) {
      u64 o = __shfl_down(m, (unsigned)off, 64);
      if (o < m) m = o;
    }
    m = __shfl(m, 0, 64);
    if (m != ~0ull) {
      if (lane == s) myidx = (int)(m & 0xffffffffu);
      mycnt++;
      thresh = m + 1;
    } else break;
  }
  if (lane < Ksel) idx[i * Ksel + lane] = myidx;
  if (lane == 0) cnt[i] = mycnt;
}

// 3-term split-bf16 MFMA stage: OUT[e][o] = sum_f X[e][f]*W[f][o] computed as
// Xhi*Whi + Xhi*Wlo + Xlo*Whi in fp32 accumulators (rel err ~2^-17).
__device__ __forceinline__ void mfma_stage(const unsigned int* xin,
                                           const u16* __restrict__ WH,
                                           const u16* __restrict__ WL,
                                           int E, int ob, int lane, f32x4 acc[4]) {
  const int l16 = lane & 15, q = lane >> 4;
  const unsigned int* xr = xin + (E * 16 + l16) * XLD + q * 8;
  f32x4 z = {0.f, 0.f, 0.f, 0.f};
  acc[0] = z; acc[1] = z; acc[2] = z; acc[3] = z;
#pragma unroll
  for (int kt = 0; kt < 4; kt++) {
    uint4 xa = *(const uint4*)(xr + kt * 32);
    uint4 xb = *(const uint4*)(xr + kt * 32 + 4);
    bf16x8 ah = mk8(__builtin_amdgcn_perm(xa.y, xa.x, PERM_HI),
                    __builtin_amdgcn_perm(xa.w, xa.z, PERM_HI),
                    __builtin_amdgcn_perm(xb.y, xb.x, PERM_HI),
                    __builtin_amdgcn_perm(xb.w, xb.z, PERM_HI));
    bf16x8 al = mk8(__builtin_amdgcn_perm(xa.y, xa.x, PERM_LO),
                    __builtin_amdgcn_perm(xa.w, xa.z, PERM_LO),
                    __builtin_amdgcn_perm(xb.y, xb.x, PERM_LO),
                    __builtin_amdgcn_perm(xb.w, xb.z, PERM_LO));
#pragma unroll
    for (int ot = 0; ot < 4; ot++) {
      const int off = ((kt * 8 + ob + ot) * 64 + lane) * 8;
      bf16x8 wh = *(const bf16x8*)(WH + off);
      bf16x8 wl = *(const bf16x8*)(WL + off);
      acc[ot] = __builtin_amdgcn_mfma_f32_16x16x32_bf16(al, wh, acc[ot], 0, 0, 0);
      acc[ot] = __builtin_amdgcn_mfma_f32_16x16x32_bf16(ah, wl, acc[ot], 0, 0, 0);
      acc[ot] = __builtin_amdgcn_mfma_f32_16x16x32_bf16(ah, wh, acc[ot], 0, 0, 0);
    }
  }
}

// ---------------- one EGNN layer, one block per 2 nodes ----------------
// Single in-place X buffer (44.5 KB LDS => 3 blocks/CU). Occupancy floor kept
// at 4 waves/EU: (512,6) clamped the unified VGPR+AGPR budget to ~85/wave,
// spilled ~48 B/thread to scratch (WRITE_SIZE 2.2 -> 49.6 MB) and regressed;
// with (512,4) the code fits (~52 arch VGPR + MFMA accs) and LDS is the
// occupancy limiter at 6 waves/EU anyway.
__global__ __launch_bounds__(512, 4) void egnn_layer(
    const float* __restrict__ h_in, const float* __restrict__ pos_in,
    float* __restrict__ h_out, float* __restrict__ pos_out,
    const int* __restrict__ idx, const int* __restrict__ cnt,
    const float* __restrict__ ew1, const float* __restrict__ eb1,
    const float* __restrict__ eb2,
    const float* __restrict__ cb1, const float* __restrict__ cw2,
    const float* __restrict__ nw1, const float* __restrict__ nb1,
    const float* __restrict__ nw2, const float* __restrict__ nb2,
    const u16* __restrict__ wbh, const u16* __restrict__ wbl) {
  __shared__ __align__(16) unsigned int xp[64 * XLD];  // packed hi|lo X, [e][f]
  __shared__ float hi_s[2][HD], hpart_s[2][HD], msum_s[2][HD], u_s[2][HD];
  __shared__ float red_s[512];
  __shared__ float msum_red[4][HD];   // per-e-tile partial msum
  __shared__ float ce_red[64][2];     // per-e partial c-dot (o halves)
  __shared__ float rel_s[3][64], d2_s[64], mf_s[64], ce_s[64];
  __shared__ int idx_s[64], cn_s[2];

  const int t = threadIdx.x;
  const int i0 = blockIdx.x * 2;
  const int e = t & 63;
  const int lane = t & 63;
  const int wid8 = __builtin_amdgcn_readfirstlane(t >> 6);  // 0..7
  const int E = wid8 & 3;            // e-tile (16 edges)
  const int ob = (wid8 >> 2) * 4;    // first o-tile (4 tiles = 64 outputs)
  const int l16 = lane & 15, q = lane >> 4;

  if (t < 64) idx_s[t] = idx[(size_t)(i0 + (t >> 5)) * KE + (t & 31)];
  else if (t < 66) cn_s[t - 64] = cnt[i0 + (t - 64)];
  if (t >= 256) {
    const int nt = t - 256;
    hi_s[nt >> 7][nt & 127] = h_in[(size_t)(i0 + (nt >> 7)) * HD + (nt & 127)];
  }
  __syncthreads();

  if (t < 64) {
    const int nd = t >> 5, ic = i0 + nd;
    const int j = idx_s[t];
    const float rx = pos_in[ic * 3 + 0] - pos_in[j * 3 + 0];
    const float ry = pos_in[ic * 3 + 1] - pos_in[j * 3 + 1];
    const float rz = pos_in[ic * 3 + 2] - pos_in[j * 3 + 2];
    rel_s[0][t] = rx; rel_s[1][t] = ry; rel_s[2][t] = rz;
    d2_s[t] = rx * rx + ry * ry + rz * rz;
    mf_s[t] = ((t & 31) < cn_s[nd]) ? 1.0f : 0.0f;
  }
  // gather hj -> xp[e][f] packed hi|lo (wave stages a 16-f slab for its cols)
  {
    const int j = idx_s[e];
    const int f0 = (t >> 6) * 16;
    const float4* src = (const float4*)(h_in + (size_t)j * HD + f0);
    unsigned int* dst = xp + e * XLD + f0;
#pragma unroll
    for (int qq = 0; qq < 4; qq++) {
      float4 v = src[qq];
      unsigned int p0, p1, p2, p3;
      packhl2(v.x, v.y, p0, p1);
      packhl2(v.z, v.w, p2, p3);
      dst[qq * 4 + 0] = p0;
      dst[qq * 4 + 1] = p1;
      dst[qq * 4 + 2] = p2;
      dst[qq * 4 + 3] = p3;
    }
  }
  // hpart[nd][o] = hi . ew1[0:128, o]  (edge-invariant half of edge MLP1)
  {
    const int oo = t & 127, nd = (t >> 7) & 1, hf = t >> 8;
    const float* hsrc = hi_s[nd];
    float hp = 0.f;
#pragma unroll
    for (int f4 = hf * 16; f4 < hf * 16 + 16; f4++) {
      float4 xv = *(const float4*)(hsrc + f4 * 4);
      hp = fmaf(xv.x, ew1[(f4 * 4 + 0) * HD + oo], hp);
      hp = fmaf(xv.y, ew1[(f4 * 4 + 1) * HD + oo], hp);
      hp = fmaf(xv.z, ew1[(f4 * 4 + 2) * HD + oo], hp);
      hp = fmaf(xv.w, ew1[(f4 * 4 + 3) * HD + oo], hp);
    }
    red_s[t] = hp;
  }
  __syncthreads();
  if (t < 256) hpart_s[t >> 7][t & 127] = red_s[t] + red_s[t + 256] + eb1[t & 127];
  __syncthreads();

  // ---- stage B: m1 = silu(hpart + hj @ ew1[128:256] + d2*ew1[256]) ----
  {
    f32x4 acc[4];
    mfma_stage(xp, wbh, wbl, E, ob, lane, acc);
    __syncthreads();  // all xp reads done before in-place overwrite
    const int nd = E >> 1;
    float d2v[4];
#pragma unroll
    for (int r = 0; r < 4; r++) d2v[r] = d2_s[E * 16 + q * 4 + r];
#pragma unroll
    for (int ot = 0; ot < 4; ot++) {
      const int o = (ob + ot) * 16 + l16;
      const float hp = hpart_s[nd][o];
      const float w2 = ew1[256 * HD + o];
      float s0 = silu_f(acc[ot][0] + hp + d2v[0] * w2);
      float s1 = silu_f(acc[ot][1] + hp + d2v[1] * w2);
      float s2 = silu_f(acc[ot][2] + hp + d2v[2] * w2);
      float s3 = silu_f(acc[ot][3] + hp + d2v[3] * w2);
      unsigned int p0, p1, p2, p3;
      packhl2(s0, s1, p0, p1);
      packhl2(s2, s3, p2, p3);
      const int eb_ = E * 16 + q * 4;
      xp[(eb_ + 0) * XLD + o] = p0;
      xp[(eb_ + 1) * XLD + o] = p1;
      xp[(eb_ + 2) * XLD + o] = p2;
      xp[(eb_ + 3) * XLD + o] = p3;
    }
  }
  __syncthreads();

  // ---- stage C: m2 = mask ? silu(m1 @ ew2 + eb2) : 0 ; msum partials ----
  {
    f32x4 acc[4];
    mfma_stage(xp, wbh + 16384, wbl + 16384, E, ob, lane, acc);
    __syncthreads();  // all xp reads done before in-place overwrite
    float mfv[4];
#pragma unroll
    for (int r = 0; r < 4; r++) mfv[r] = mf_s[E * 16 + q * 4 + r];
    float msp[4] = {0.f, 0.f, 0.f, 0.f};
#pragma unroll
    for (int ot = 0; ot < 4; ot++) {
      const int o = (ob + ot) * 16 + l16;
      const float bb = eb2[o];
      float mm[4];
#pragma unroll
      for (int r = 0; r < 4; r++) {
        mm[r] = (mfv[r] != 0.f) ? silu_f(acc[ot][r] + bb) : 0.f;
        msp[ot] += mm[r];
      }
      unsigned int p0, p1, p2, p3;
      packhl2(mm[0], mm[1], p0, p1);
      packhl2(mm[2], mm[3], p2, p3);
      const int eb_ = E * 16 + q * 4;
      xp[(eb_ + 0) * XLD + o] = p0;
      xp[(eb_ + 1) * XLD + o] = p1;
      xp[(eb_ + 2) * XLD + o] = p2;
      xp[(eb_ + 3) * XLD + o] = p3;
    }
    // reduce msum over the 4 q-groups (e within tile); write per-tile partial
#pragma unroll
    for (int ot = 0; ot < 4; ot++) {
      float s = msp[ot];
      s += __shfl_xor(s, 16);
      s += __shfl_xor(s, 32);
      msp[ot] = s;
    }
    if (lane < 16) {
#pragma unroll
      for (int ot = 0; ot < 4; ot++) msum_red[E][(ob + ot) * 16 + lane] = msp[ot];
    }
  }
  __syncthreads();

  // ---- stage D: c1 = silu(m2 @ cw1 + cb1); fold cw2 dot in-register ----
  {
    f32x4 acc[4];
    mfma_stage(xp, wbh + 32768, wbl + 32768, E, ob, lane, acc);
    float cp[4] = {0.f, 0.f, 0.f, 0.f};
#pragma unroll
    for (int ot = 0; ot < 4; ot++) {
      const int o = (ob + ot) * 16 + l16;
      const float b1 = cb1[o];
      const float c2 = cw2[o];
#pragma unroll
      for (int r = 0; r < 4; r++)
        cp[r] = fmaf(silu_f(acc[ot][r] + b1), c2, cp[r]);
    }
#pragma unroll
    for (int r = 0; r < 4; r++) {
      float s = cp[r];
      s += __shfl_xor(s, 1);
      s += __shfl_xor(s, 2);
      s += __shfl_xor(s, 4);
      s += __shfl_xor(s, 8);
      cp[r] = s;
    }
    if (l16 == 0) {
#pragma unroll
      for (int r = 0; r < 4; r++) ce_red[E * 16 + q * 4 + r][ob >> 2] = cp[r];
    }
  }
  __syncthreads();
  if (t < 64) ce_s[t] = (mf_s[t] != 0.f) ? (ce_red[t][0] + ce_red[t][1]) : 0.f;
  if (t < 256) {
    const int nd = t >> 7, oo = t & 127;
    msum_s[nd][oo] = msum_red[nd * 2][oo] + msum_red[nd * 2 + 1][oo];
  }
  __syncthreads();
  // ---- pos update ----
  if (t < 6) {
    const int nd = t / 3, ax = t - nd * 3, ic = i0 + nd;
    float s = 0.f;
#pragma unroll
    for (int k = 0; k < 32; k++) s = fmaf(rel_s[ax][nd * 32 + k], ce_s[nd * 32 + k], s);
    const float cntf = fmaxf((float)cn_s[nd], 1.f);
    pos_out[ic * 3 + ax] = pos_in[ic * 3 + ax] + s / cntf;
  }
  // ---- node MLP1 ----
  {
    const int oo = t & 127, nd = (t >> 7) & 1, ph = t >> 8;
    const float* src = ph ? msum_s[nd] : hi_s[nd];
    const float* Wp = nw1 + (size_t)ph * 128 * HD + oo;
    float p = 0.f;
#pragma unroll
    for (int f4 = 0; f4 < 32; f4++) {
      float4 xv = *(const float4*)(src + f4 * 4);
      p = fmaf(xv.x, Wp[(f4 * 4 + 0) * HD], p);
      p = fmaf(xv.y, Wp[(f4 * 4 + 1) * HD], p);
      p = fmaf(xv.z, Wp[(f4 * 4 + 2) * HD], p);
      p = fmaf(xv.w, Wp[(f4 * 4 + 3) * HD], p);
    }
    red_s[t] = p;
  }
  __syncthreads();
  if (t < 256) u_s[t >> 7][t & 127] = silu_f(red_s[t] + red_s[t + 256] + nb1[t & 127]);
  __syncthreads();
  // ---- node MLP2 + residual ----
  {
    const int oo = t & 127, nd = (t >> 7) & 1, ph = t >> 8;
    const float* src = u_s[nd] + ph * 64;
    const float* Wp = nw2 + (size_t)ph * 64 * HD + oo;
    float p = 0.f;
#pragma unroll
    for (int f4 = 0; f4 < 16; f4++) {
      float4 xv = *(const float4*)(src + f4 * 4);
      p = fmaf(xv.x, Wp[(f4 * 4 + 0) * HD], p);
      p = fmaf(xv.y, Wp[(f4 * 4 + 1) * HD], p);
      p = fmaf(xv.z, Wp[(f4 * 4 + 2) * HD], p);
      p = fmaf(xv.w, Wp[(f4 * 4 + 3) * HD], p);
    }
    red_s[t] = p;
  }
  __syncthreads();
  if (t < 256) {
    const int nd = t >> 7, oo = t & 127;
    h_out[(size_t)(i0 + nd) * HD + oo] = hi_s[nd][oo] + red_s[t] + red_s[t + 256] + nb2[oo];
  }
}

// ---------------- final heads (per node) ----------------
__global__ __launch_bounds__(256) void heads_kernel(
    const float* __restrict__ h, const float* __restrict__ pos,
    const float* __restrict__ fw1, const float* __restrict__ fb1,
    const float* __restrict__ fw2, const float* __restrict__ fb2,
    const float* __restrict__ cw1g, const float* __restrict__ cb1g,
    const float* __restrict__ cw2g, const float* __restrict__ cb2g,
    const float* __restrict__ sw, const float* __restrict__ sb,
    const float* __restrict__ iw,
    float* __restrict__ At, float* __restrict__ Bt,
    void* __restrict__ out, const int* __restrict__ flag) {
  __shared__ float hi_s[HD], v1[HD], red_s[256];
  const int i = blockIdx.x, t = threadIdx.x;
  const int fm = *flag;
  if (t < HD) hi_s[t] = h[(size_t)i * HD + t];
  __syncthreads();
  const int o = t & 127, ph = t >> 7;
  // forces MLP1
  {
    float p = 0.f;
#pragma unroll 4
    for (int f = ph * 64; f < ph * 64 + 64; f++) p = fmaf(hi_s[f], fw1[f * HD + o], p);
    red_s[t] = p;
  }
  __syncthreads();
  if (t < HD) v1[t] = tanhf(red_s[t] + red_s[t + 128] + fb1[t]);
  __syncthreads();
  if (t < 3) {
    float p = 0.f;
    for (int f = 0; f < HD; f++) p = fmaf(v1[f], fw2[f * 3 + t], p);
    stout(out, fm, OFF_F + (size_t)i * 3 + t, p + fb2[t]);
  }
  __syncthreads();
  // conformer MLP1
  {
    float p = 0.f;
#pragma unroll 4
    for (int f = ph * 64; f < ph * 64 + 64; f++) p = fmaf(hi_s[f], cw1g[f * HD + o], p);
    red_s[t] = p;
  }
  __syncthreads();
  if (t < HD) v1[t] = fmaxf(red_s[t] + red_s[t + 128] + cb1g[t], 0.f);
  __syncthreads();
  // conformer MLP2
  {
    const int oo = t & 63, pc = t >> 6;
    float p = 0.f;
#pragma unroll 4
    for (int f = pc * 32; f < pc * 32 + 32; f++) p = fmaf(v1[f], cw2g[f * 64 + oo], p);
    red_s[t] = p;
  }
  __syncthreads();
  if (t < 64)
    stout(out, fm, OFF_C + (size_t)i * 64 + t,
          red_s[t] + red_s[t + 64] + red_s[t + 128] + red_s[t + 192] + cb2g[t]);
  __syncthreads();
  // steric
  if (t < HD) red_s[t] = hi_s[t] * sw[t];
  __syncthreads();
  if (t == 0) {
    float p = 0.f;
    for (int f = 0; f < HD; f++) p += red_s[f];
    stout(out, fm, OFF_ST + (size_t)i, p + sb[0]);
  }
  __syncthreads();
  // interaction head per-node dots
  {
    const int g = t >> 5, l = t & 31;
    float p = 0.f;
    if (g < 6) {
      const int tt = g >> 1, half = g & 1;
#pragma unroll
      for (int r2 = 0; r2 < 4; r2++)
        p = fmaf(hi_s[l * 4 + r2], iw[tt * 258 + half * 128 + l * 4 + r2], p);
    }
    red_s[t] = p;
  }
  __syncthreads();
  if (t < 6) {
    float p = 0.f;
    for (int l = 0; l < 32; l++) p += red_s[t * 32 + l];
    const int tt = t >> 1;
    if ((t & 1) == 0) At[tt * NN + i] = p;
    else Bt[tt * NN + i] = p;
  }
  if (t < HD) stout(out, fm, OFF_H + (size_t)i * HD + t, hi_s[t]);
  if (t >= 128 && t < 131) stout(out, fm, OFF_POS + (size_t)i * 3 + (t - 128), pos[i * 3 + (t - 128)]);
}

// ---------------- interaction scores ----------------
__global__ void scores_kernel(const float* __restrict__ pos, const int* __restrict__ idx2,
                              const int* __restrict__ cnt2, const float* __restrict__ At,
                              const float* __restrict__ Bt, const float* __restrict__ iw,
                              const float* __restrict__ ib, void* __restrict__ out,
                              const int* __restrict__ flag) {
  int tid = blockIdx.x * 256 + threadIdx.x;
  if (tid >= 3 * NN * KI) return;
  const int fm = *flag;
  const int tt = tid / (NN * KI);
  const int r = tid % (NN * KI);
  const int n = r / KI;
  const int k = r % KI;
  float v = 0.f;
  if (k < cnt2[n]) {
    int j = idx2[n * KI + k];
    float dx = pos[n * 3 + 0] - pos[j * 3 + 0];
    float dy = pos[n * 3 + 1] - pos[j * 3 + 1];
    float dz = pos[n * 3 + 2] - pos[j * 3 + 2];
    float d2 = dx * dx + dy * dy + dz * dz;
    float dist = sqrtf(d2 + 1e-12f);
    float s = At[tt * NN + n] + Bt[tt * NN + j] + dist * iw[tt * 258 + 256] +
              (dist * 0.1f) * iw[tt * 258 + 257] + ib[tt];
    v = 1.f / (1.f + __expf(-s));
  }
  stout(out, fm, OFF_S + (size_t)tid, v);
}

extern "C" void kernel_launch(void* const* d_in, const int* in_sizes, int n_in,
                              void* d_out, int out_size, void* d_ws, size_t ws_size,
                              hipStream_t stream) {
  (void)in_sizes; (void)n_in; (void)out_size; (void)ws_size;

  float* wsf = (float*)d_ws;
  float* h_a = wsf + 0;             // 524288
  float* pos_a = wsf + 524288;      // 12288
  float* h_b = wsf + 536576;        // 524288
  float* pos_b = wsf + 1060864;     // 12288
  float* At = wsf + 1073152;        // 12288
  float* Bt = wsf + 1085440;        // 12288
  const int W0 = 1097728;

  static const int wcnt[23] = {197376, 768, 98304, 768, 98304, 768, 768,
                               196608, 768, 98304, 768, 16384, 128, 384, 3,
                               774, 3, 16384, 128, 8192, 64, 128, 1};
  int woff[23];
  {
    int o = W0;
    for (int k = 0; k < 23; k++) { woff[k] = o; o += wcnt[k]; }
  }
  const int IOFF = woff[22] + wcnt[22];
  int* ibase = (int*)d_ws;
  int* idx1 = ibase + IOFF;
  int* cnt1 = idx1 + NN * KE;
  int* idx2 = cnt1 + NN;
  int* cnt2 = idx2 + NN * KI;
  int* gstart = cnt2 + NN;
  int* flag = gstart + 33;
  // packed MFMA weight fragments (bf16 hi/lo), 16B-aligned
  int wboff = (int)((flag + 1) - ibase);
  wboff = (wboff + 3) & ~3;
  u16* WBH = (u16*)(ibase + wboff);
  u16* WBL = WBH + 18 * 16384;

  const float* EW1 = wsf + woff[0];
  const float* EB1 = wsf + woff[1];
  const float* EB2 = wsf + woff[3];
  const float* CB1 = wsf + woff[5];
  const float* CW2 = wsf + woff[6];
  const float* NW1 = wsf + woff[7];
  const float* NB1 = wsf + woff[8];
  const float* NW2 = wsf + woff[9];
  const float* NB2 = wsf + woff[10];
  const float* FW1 = wsf + woff[11];
  const float* FB1 = wsf + woff[12];
  const float* FW2 = wsf + woff[13];
  const float* FB2 = wsf + woff[14];
  const float* IW = wsf + woff[15];
  const float* IB = wsf + woff[16];
  const float* CW1G = wsf + woff[17];
  const float* CB1G = wsf + woff[18];
  const float* CW2G = wsf + woff[19];
  const float* CB2G = wsf + woff[20];
  const float* SW = wsf + woff[21];
  const float* SB = wsf + woff[22];

  probe_dtype<<<1, 256, 0, stream>>>((const u16*)d_in[0], flag);

  CvtTable tab;
  tab.src[0] = d_in[0]; tab.dstoff[0] = 0;       tab.cnt[0] = NN * HD;
  tab.src[1] = d_in[1]; tab.dstoff[1] = 524288;  tab.cnt[1] = NN * 3;
  for (int k = 0; k < 23; k++) {
    tab.src[2 + k] = d_in[3 + k];
    tab.dstoff[2 + k] = woff[k];
    tab.cnt[2 + k] = wcnt[k];
  }
  {
    dim3 g((NN * HD + 255) / 256, 25, 1);
    convert_all<<<g, 256, 0, stream>>>(tab, wsf, flag);
  }
  pack_weights<<<(18 * 16384 + 255) / 256, 256, 0, stream>>>(
      wsf, woff[0], woff[2], woff[4], WBH, WBL);

  const int* batch = (const int*)d_in[2];
  graph_bounds<<<NN / 256, 256, 0, stream>>>(batch, gstart);

  const float cut2s[3] = {9.f, 36.f, 100.f};
  float *hin = h_a, *pin = pos_a, *hout = h_b, *pout = pos_b;
  for (int l = 0; l < 6; l++) {
    if ((l & 1) == 0)
      neigh_kernel<<<NN / 4, 256, 0, stream>>>(pin, batch, gstart, idx1, cnt1, KE, cut2s[l >> 1]);
    egnn_layer<<<NN / 2, 512, 0, stream>>>(
        hin, pin, hout, pout, idx1, cnt1,
        EW1 + (size_t)l * 257 * HD, EB1 + (size_t)l * HD,
        EB2 + (size_t)l * HD,
        CB1 + (size_t)l * HD, CW2 + (size_t)l * HD,
        NW1 + (size_t)l * 256 * HD, NB1 + (size_t)l * HD,
        NW2 + (size_t)l * HD * HD, NB2 + (size_t)l * HD,
        WBH + (size_t)l * 3 * 16384, WBL + (size_t)l * 3 * 16384);
    float* th = hin; hin = hout; hout = th;
    float* tp = pin; pin = pout; pout = tp;
  }
  neigh_kernel<<<NN / 4, 256, 0, stream>>>(pin, batch, gstart, idx2, cnt2, KI, 100.f);
  heads_kernel<<<NN, 256, 0, stream>>>(hin, pin, FW1, FB1, FW2, FB2, CW1G, CB1G, CW2G, CB2G,
                                       SW, SB, IW, At, Bt, d_out, flag);
  scores_kernel<<<(3 * NN * KI + 255) / 256, 256, 0, stream>>>(
      pin, idx2, cnt2, At, Bt, IW, IB, d_out, flag);
}

// Round 5
// 867.166 us; speedup vs baseline: 1.3509x; 1.0908x over previous
//
#include <hip/hip_runtime.h>
#include <hip/hip_bf16.h>

#define NN 4096
#define HD 128
#define KE 32
#define KI 20
#define XLD 132   // X LDS row stride in u32 (16B-aligned rows)
#define PLOF 68   // lo-plane column offset within a row (16B-aligned)

// output element offsets
#define OFF_H   0
#define OFF_POS 524288
#define OFF_F   536576
#define OFF_S   548864
#define OFF_C   794624
#define OFF_ST  1056768

typedef unsigned short u16;
typedef unsigned int u32;
typedef unsigned long long u64;
typedef __attribute__((ext_vector_type(8))) short bf16x8;   // 8 bf16 (4 VGPR)
typedef __attribute__((ext_vector_type(4))) float f32x4;

#define PERM_HI 0x07060302u
#define PERM_LO 0x05040100u

__device__ __forceinline__ float b2f(u16 u) {
  union { u32 i; float f; } c; c.i = ((u32)u) << 16; return c.f;
}
__device__ __forceinline__ float silu_f(float x) { return x / (1.f + __expf(-x)); }
__device__ __forceinline__ void stout(void* out, int fp32m, size_t i, float v) {
  if (fp32m) ((float*)out)[i] = v;
  else ((__hip_bfloat16*)out)[i] = __float2bfloat16(v);
}
// RNE float->bf16 bits (reference path, used in pack_weights)
__device__ __forceinline__ u32 f2b(float f) {
  u32 u = __float_as_uint(f);
  return (u + 0x7fffu + ((u >> 16) & 1u)) >> 16;
}
// hi/lo split of two values -> interleaved per-value words [hi|lo]
__device__ __forceinline__ void packhl2(float a, float b, u32& pa, u32& pb) {
  u32 H, L;
  asm("v_cvt_pk_bf16_f32 %0, %1, %2" : "=v"(H) : "v"(a), "v"(b));
  float hfa = __uint_as_float(H << 16);
  float hfb = __uint_as_float(H & 0xffff0000u);
  asm("v_cvt_pk_bf16_f32 %0, %1, %2" : "=v"(L) : "v"(a - hfa), "v"(b - hfb));
  pa = __builtin_amdgcn_perm(H, L, PERM_LO);
  pb = __builtin_amdgcn_perm(H, L, PERM_HI);
}
// hi/lo split of two f-adjacent values -> plane words (H=[b:a] hi, L=[b:a] lo)
__device__ __forceinline__ void packplane(float a, float b, u32& H, u32& L) {
  asm("v_cvt_pk_bf16_f32 %0, %1, %2" : "=v"(H) : "v"(a), "v"(b));
  float hfa = __uint_as_float(H << 16);
  float hfb = __uint_as_float(H & 0xffff0000u);
  asm("v_cvt_pk_bf16_f32 %0, %1, %2" : "=v"(L) : "v"(a - hfa), "v"(b - hfb));
}
__device__ __forceinline__ bf16x8 mk8(u32 a, u32 b, u32 c, u32 d) {
  union { u32 u[4]; bf16x8 v; } t;
  t.u[0] = a; t.u[1] = b; t.u[2] = c; t.u[3] = d; return t.v;
}

// ---------------- dtype probe ----------------
__global__ void probe_dtype(const u16* __restrict__ h, int* __restrict__ flag) {
  if (threadIdx.x == 0) atomicExch(flag, 0);
  __syncthreads();
  int bad = 0;
  for (int i = threadIdx.x; i < 8192; i += 256) {
    float v = b2f(h[i]);
    if (!(v > -1000.f && v < 1000.f)) bad = 1;
  }
  if (bad) atomicOr(flag, 1);
}

// ---------------- convert all float tensors -> fp32 workspace ----------------
struct CvtTable {
  const void* src[25];
  int dstoff[25];
  int cnt[25];
};

__global__ void convert_all(CvtTable tab, float* __restrict__ wsf, const int* __restrict__ flag) {
  const int seg = blockIdx.y;
  const int i = blockIdx.x * 256 + threadIdx.x;
  if (i >= tab.cnt[seg]) return;
  float v;
  if (*flag) v = ((const float*)tab.src[seg])[i];
  else       v = b2f(((const u16*)tab.src[seg])[i]);
  wsf[tab.dstoff[seg] + i] = v;
}

// ------- pack stage weights: interleaved hi/lo MFMA B-fragments -------
// Layout: [mat 18][kt 4][ot 8][lane 64][16 u16] where [0..8)=hi j, [8..16)=lo j.
// One fragment-pair = 32 contiguous bytes: wh at +0, wl at +16 (imm offset).
__global__ void pack_weights(const float* __restrict__ wsf, int offEW1, int offEW2, int offCW1,
                             u16* __restrict__ WBP) {
  int tid = blockIdx.x * 256 + threadIdx.x;
  if (tid >= 18 * 32768) return;
  int m = tid >> 15;
  int rix = tid & 32767;
  int layer = m / 3, s = m % 3;
  const float* src;
  if (s == 0)      src = wsf + offEW1 + (size_t)layer * 257 * HD + 128 * HD;
  else if (s == 1) src = wsf + offEW2 + (size_t)layer * HD * HD;
  else             src = wsf + offCW1 + (size_t)layer * HD * HD;
  int jh = rix & 15, lane = (rix >> 4) & 63, ot = (rix >> 10) & 7, kt = rix >> 13;
  int j = jh & 7;
  int f = kt * 32 + (lane >> 4) * 8 + j;
  int o = ot * 16 + (lane & 15);
  float v = src[f * HD + o];
  u32 hb = f2b(v);
  float hf = __uint_as_float(hb << 16);
  u32 lb = f2b(v - hf);
  WBP[tid] = (jh < 8) ? (u16)hb : (u16)lb;
}

// ---------------- graph boundaries from sorted batch ----------------
__global__ void graph_bounds(const int* __restrict__ batch, int* __restrict__ gstart) {
  int n = blockIdx.x * 256 + threadIdx.x;
  if (n >= NN) return;
  int v = batch[n];
  int pv = (n == 0) ? -1 : batch[n - 1];
  for (int b = pv + 1; b <= v; b++) gstart[b] = n;
  if (n == NN - 1) for (int b = v + 1; b <= 32; b++) gstart[b] = NN;
}

// ---------------- exact k-NN within cutoff (one wave per node) ----------------
__global__ __launch_bounds__(256) void neigh_kernel(
    const float* __restrict__ pos, const int* __restrict__ batch,
    const int* __restrict__ gstart, int* __restrict__ idx, int* __restrict__ cnt,
    int Ksel, float cut2) {
  const int lane = threadIdx.x & 63;
  const int i = blockIdx.x * 4 + (threadIdx.x >> 6);
  const int b = batch[i];
  const int gs = gstart[b];
  const int ge = gstart[b + 1];
  const int span = ge - gs;
  const float px = pos[i * 3 + 0], py = pos[i * 3 + 1], pz = pos[i * 3 + 2];
  u64 key[16];
#pragma unroll
  for (int tq = 0; tq < 16; tq++) {
    u64 k64 = ~0ull;
    if (tq * 64 < span) {
      int j = gs + tq * 64 + lane;
      if (j < ge && j != i) {
        float dx = px - pos[j * 3 + 0];
        float dy = py - pos[j * 3 + 1];
        float dz = pz - pos[j * 3 + 2];
        float d2 = dx * dx + dy * dy + dz * dz;
        if (d2 <= cut2) k64 = (((u64)__float_as_uint(d2)) << 32) | (u32)j;
      }
    }
    key[tq] = k64;
  }
  u64 thresh = 0;
  int myidx = i;
  int mycnt = 0;
  for (int s = 0; s < Ksel; s++) {
    u64 m = ~0ull;
#pragma unroll
    for (int tq = 0; tq < 16; tq++) {
      if (tq * 64 < span) {
        u64 kk = key[tq];
        if (kk >= thresh && kk < m) m = kk;
      }
    }
    for (int off = 32; off > 0; off >>= 1) {
      u64 o = __shfl_down(m, (unsigned)off, 64);
      if (o < m) m = o;
    }
    m = __shfl(m, 0, 64);
    if (m != ~0ull) {
      if (lane == s) myidx = (int)(m & 0xffffffffu);
      mycnt++;
      thresh = m + 1;
    } else break;
  }
  if (lane < Ksel) idx[i * Ksel + lane] = myidx;
  if (lane == 0) cnt[i] = mycnt;
}

// 3-term split-bf16 MFMA stage, plane-layout X (stage B: no perms).
// Wave w owns o-tile w (16 outputs), all 4 e-tiles. Per stage: 4 B-frag-pair
// loads total (kt=0..3), hoistable to stage start -> no mid-stage L2 latency.
__device__ __forceinline__ void mfma_stageP(const u32* xp_, const u16* __restrict__ WP,
                                            int w, int lane, f32x4 acc[4]) {
  const int l16 = lane & 15, q = lane >> 4;
  f32x4 z = {0.f, 0.f, 0.f, 0.f};
  acc[0] = z; acc[1] = z; acc[2] = z; acc[3] = z;
#pragma unroll
  for (int kt = 0; kt < 4; kt++) {
    const u16* wb = WP + (size_t)(((kt * 8 + w) * 64 + lane)) * 16;
    bf16x8 wh = *(const bf16x8*)(wb);
    bf16x8 wl = *(const bf16x8*)(wb + 8);
#pragma unroll
    for (int Et = 0; Et < 4; Et++) {
      const u32* xr = xp_ + (Et * 16 + l16) * XLD + kt * 16 + q * 4;
      bf16x8 ah = *(const bf16x8*)(xr);
      bf16x8 al = *(const bf16x8*)(xr + PLOF);
      acc[Et] = __builtin_amdgcn_mfma_f32_16x16x32_bf16(al, wh, acc[Et], 0, 0, 0);
      acc[Et] = __builtin_amdgcn_mfma_f32_16x16x32_bf16(ah, wl, acc[Et], 0, 0, 0);
      acc[Et] = __builtin_amdgcn_mfma_f32_16x16x32_bf16(ah, wh, acc[Et], 0, 0, 0);
    }
  }
}

// Same, interleaved-layout X (stages C/D: per-value [hi|lo] words + perms).
__device__ __forceinline__ void mfma_stageI(const u32* xp_, const u16* __restrict__ WP,
                                            int w, int lane, f32x4 acc[4]) {
  const int l16 = lane & 15, q = lane >> 4;
  f32x4 z = {0.f, 0.f, 0.f, 0.f};
  acc[0] = z; acc[1] = z; acc[2] = z; acc[3] = z;
#pragma unroll
  for (int kt = 0; kt < 4; kt++) {
    const u16* wb = WP + (size_t)(((kt * 8 + w) * 64 + lane)) * 16;
    bf16x8 wh = *(const bf16x8*)(wb);
    bf16x8 wl = *(const bf16x8*)(wb + 8);
#pragma unroll
    for (int Et = 0; Et < 4; Et++) {
      const u32* xr = xp_ + (Et * 16 + l16) * XLD + kt * 32 + q * 8;
      uint4 xa = *(const uint4*)(xr);
      uint4 xb = *(const uint4*)(xr + 4);
      bf16x8 ah = mk8(__builtin_amdgcn_perm(xa.y, xa.x, PERM_HI),
                      __builtin_amdgcn_perm(xa.w, xa.z, PERM_HI),
                      __builtin_amdgcn_perm(xb.y, xb.x, PERM_HI),
                      __builtin_amdgcn_perm(xb.w, xb.z, PERM_HI));
      bf16x8 al = mk8(__builtin_amdgcn_perm(xa.y, xa.x, PERM_LO),
                      __builtin_amdgcn_perm(xa.w, xa.z, PERM_LO),
                      __builtin_amdgcn_perm(xb.y, xb.x, PERM_LO),
                      __builtin_amdgcn_perm(xb.w, xb.z, PERM_LO));
      acc[Et] = __builtin_amdgcn_mfma_f32_16x16x32_bf16(al, wh, acc[Et], 0, 0, 0);
      acc[Et] = __builtin_amdgcn_mfma_f32_16x16x32_bf16(ah, wl, acc[Et], 0, 0, 0);
      acc[Et] = __builtin_amdgcn_mfma_f32_16x16x32_bf16(ah, wh, acc[Et], 0, 0, 0);
    }
  }
}

// ---------------- one EGNN layer, one block per 2 nodes ----------------
__global__ __launch_bounds__(512, 4) void egnn_layer(
    const float* __restrict__ h_in, const float* __restrict__ pos_in,
    float* __restrict__ h_out, float* __restrict__ pos_out,
    const int* __restrict__ idx, const int* __restrict__ cnt,
    const float* __restrict__ ew1, const float* __restrict__ eb1,
    const float* __restrict__ eb2,
    const float* __restrict__ cb1, const float* __restrict__ cw2,
    const float* __restrict__ nw1, const float* __restrict__ nb1,
    const float* __restrict__ nw2, const float* __restrict__ nb2,
    const u16* __restrict__ wbp) {
  __shared__ __align__(16) u32 xp[64 * XLD];  // X: planes (B) / interleaved (C,D)
  __shared__ float hi_s[2][HD], hpart_s[2][HD], msum_s[2][HD], u_s[2][HD];
  __shared__ float red_s[512];
  __shared__ float ce_red[64][8];
  __shared__ float rel_s[3][64], d2_s[64], mf_s[64], ce_s[64];
  __shared__ int idx_s[64], cn_s[2];

  const int t = threadIdx.x;
  const int i0 = blockIdx.x * 2;
  const int e = t & 63;
  const int lane = t & 63;
  const int w = __builtin_amdgcn_readfirstlane(t >> 6);  // wave's o-tile, 0..7
  const int l16 = lane & 15, q = lane >> 4;
  const int o = w * 16 + l16;                            // wave-owned output col

  if (t < 64) idx_s[t] = idx[(size_t)(i0 + (t >> 5)) * KE + (t & 31)];
  else if (t < 66) cn_s[t - 64] = cnt[i0 + (t - 64)];
  if (t >= 256) {
    const int nt = t - 256;
    hi_s[nt >> 7][nt & 127] = h_in[(size_t)(i0 + (nt >> 7)) * HD + (nt & 127)];
  }
  __syncthreads();

  if (t < 64) {
    const int nd = t >> 5, ic = i0 + nd;
    const int j = idx_s[t];
    const float rx = pos_in[ic * 3 + 0] - pos_in[j * 3 + 0];
    const float ry = pos_in[ic * 3 + 1] - pos_in[j * 3 + 1];
    const float rz = pos_in[ic * 3 + 2] - pos_in[j * 3 + 2];
    rel_s[0][t] = rx; rel_s[1][t] = ry; rel_s[2][t] = rz;
    d2_s[t] = rx * rx + ry * ry + rz * rz;
    mf_s[t] = ((t & 31) < cn_s[nd]) ? 1.0f : 0.0f;
  }
  // gather hj -> hi/lo planes (pairs along f: no perms here or in stage B)
  {
    const int j = idx_s[e];
    const int f0 = (t >> 6) * 16;
    const float4* src = (const float4*)(h_in + (size_t)j * HD + f0);
    u32* dh = xp + e * XLD + (f0 >> 1);
#pragma unroll
    for (int qq = 0; qq < 4; qq++) {
      float4 v = src[qq];
      u32 H0, L0, H1, L1;
      packplane(v.x, v.y, H0, L0);
      packplane(v.z, v.w, H1, L1);
      uint2 hh; hh.x = H0; hh.y = H1;
      uint2 ll; ll.x = L0; ll.y = L1;
      *(uint2*)(dh + qq * 2) = hh;
      *(uint2*)(dh + PLOF + qq * 2) = ll;
    }
  }
  // hpart[nd][o] = hi . ew1[0:128, o]
  {
    const int oo = t & 127, nd = (t >> 7) & 1, hf = t >> 8;
    const float* hsrc = hi_s[nd];
    float hp = 0.f;
#pragma unroll
    for (int f4 = hf * 16; f4 < hf * 16 + 16; f4++) {
      float4 xv = *(const float4*)(hsrc + f4 * 4);
      hp = fmaf(xv.x, ew1[(f4 * 4 + 0) * HD + oo], hp);
      hp = fmaf(xv.y, ew1[(f4 * 4 + 1) * HD + oo], hp);
      hp = fmaf(xv.z, ew1[(f4 * 4 + 2) * HD + oo], hp);
      hp = fmaf(xv.w, ew1[(f4 * 4 + 3) * HD + oo], hp);
    }
    red_s[t] = hp;
  }
  __syncthreads();
  if (t < 256) hpart_s[t >> 7][t & 127] = red_s[t] + red_s[t + 256] + eb1[t & 127];
  __syncthreads();

  // ---- stage B: m1 = silu(hpart + hj @ ew1[128:256] + d2*ew1[256]) ----
  {
    f32x4 acc[4];
    mfma_stageP(xp, wbp, w, lane, acc);
    __syncthreads();  // all plane reads done before interleaved overwrite
    const float w2 = ew1[256 * HD + o];
#pragma unroll
    for (int Et = 0; Et < 4; Et++) {
      const float hp = hpart_s[Et >> 1][o];
      const int e0 = Et * 16 + q * 4;
      float s0 = silu_f(acc[Et][0] + hp + d2_s[e0 + 0] * w2);
      float s1 = silu_f(acc[Et][1] + hp + d2_s[e0 + 1] * w2);
      float s2 = silu_f(acc[Et][2] + hp + d2_s[e0 + 2] * w2);
      float s3 = silu_f(acc[Et][3] + hp + d2_s[e0 + 3] * w2);
      u32 p0, p1, p2, p3;
      packhl2(s0, s1, p0, p1);
      packhl2(s2, s3, p2, p3);
      u32* dst = xp + e0 * XLD + o;
      dst[0] = p0; dst[XLD] = p1; dst[2 * XLD] = p2; dst[3 * XLD] = p3;
    }
  }
  __syncthreads();

  // ---- stage C: m2 = mask ? silu(m1 @ ew2 + eb2) : 0 ; msum per node ----
  {
    f32x4 acc[4];
    mfma_stageI(xp, wbp + 32768, w, lane, acc);
    __syncthreads();  // all reads done before in-place overwrite
    const float bb = eb2[o];
    float ms0 = 0.f, ms1 = 0.f;
#pragma unroll
    for (int Et = 0; Et < 4; Et++) {
      const int e0 = Et * 16 + q * 4;
      float mm0 = (mf_s[e0 + 0] != 0.f) ? silu_f(acc[Et][0] + bb) : 0.f;
      float mm1 = (mf_s[e0 + 1] != 0.f) ? silu_f(acc[Et][1] + bb) : 0.f;
      float mm2 = (mf_s[e0 + 2] != 0.f) ? silu_f(acc[Et][2] + bb) : 0.f;
      float mm3 = (mf_s[e0 + 3] != 0.f) ? silu_f(acc[Et][3] + bb) : 0.f;
      if (Et < 2) { ms0 += mm0; ms0 += mm1; ms0 += mm2; ms0 += mm3; }
      else        { ms1 += mm0; ms1 += mm1; ms1 += mm2; ms1 += mm3; }
      u32 p0, p1, p2, p3;
      packhl2(mm0, mm1, p0, p1);
      packhl2(mm2, mm3, p2, p3);
      u32* dst = xp + e0 * XLD + o;
      dst[0] = p0; dst[XLD] = p1; dst[2 * XLD] = p2; dst[3 * XLD] = p3;
    }
    ms0 += __shfl_xor(ms0, 16); ms0 += __shfl_xor(ms0, 32);
    ms1 += __shfl_xor(ms1, 16); ms1 += __shfl_xor(ms1, 32);
    if (lane < 16) {
      msum_s[0][w * 16 + lane] = ms0;
      msum_s[1][w * 16 + lane] = ms1;
    }
  }
  __syncthreads();

  // ---- stage D: c1 = silu(m2 @ cw1 + cb1); fold cw2 dot; per-e partials ----
  {
    f32x4 acc[4];
    mfma_stageI(xp, wbp + 65536, w, lane, acc);
    const float b1 = cb1[o], c2 = cw2[o];
#pragma unroll
    for (int Et = 0; Et < 4; Et++) {
      const int e0 = Et * 16 + q * 4;
#pragma unroll
      for (int r = 0; r < 4; r++) {
        float p = silu_f(acc[Et][r] + b1) * c2;
        p += __shfl_xor(p, 1);
        p += __shfl_xor(p, 2);
        p += __shfl_xor(p, 4);
        p += __shfl_xor(p, 8);
        if (l16 == 0) ce_red[e0 + r][w] = p;
      }
    }
  }
  __syncthreads();
  if (t < 64) {
    float c = 0.f;
#pragma unroll
    for (int wv = 0; wv < 8; wv++) c += ce_red[t][wv];
    ce_s[t] = (mf_s[t] != 0.f) ? c : 0.f;
  }
  __syncthreads();
  // ---- pos update ----
  if (t < 6) {
    const int nd = t / 3, ax = t - nd * 3, ic = i0 + nd;
    float s = 0.f;
#pragma unroll
    for (int k = 0; k < 32; k++) s = fmaf(rel_s[ax][nd * 32 + k], ce_s[nd * 32 + k], s);
    const float cntf = fmaxf((float)cn_s[nd], 1.f);
    pos_out[ic * 3 + ax] = pos_in[ic * 3 + ax] + s / cntf;
  }
  // ---- node MLP1 ----
  {
    const int oo = t & 127, nd = (t >> 7) & 1, ph = t >> 8;
    const float* src = ph ? msum_s[nd] : hi_s[nd];
    const float* Wp = nw1 + (size_t)ph * 128 * HD + oo;
    float p = 0.f;
#pragma unroll
    for (int f4 = 0; f4 < 32; f4++) {
      float4 xv = *(const float4*)(src + f4 * 4);
      p = fmaf(xv.x, Wp[(f4 * 4 + 0) * HD], p);
      p = fmaf(xv.y, Wp[(f4 * 4 + 1) * HD], p);
      p = fmaf(xv.z, Wp[(f4 * 4 + 2) * HD], p);
      p = fmaf(xv.w, Wp[(f4 * 4 + 3) * HD], p);
    }
    red_s[t] = p;
  }
  __syncthreads();
  if (t < 256) u_s[t >> 7][t & 127] = silu_f(red_s[t] + red_s[t + 256] + nb1[t & 127]);
  __syncthreads();
  // ---- node MLP2 + residual ----
  {
    const int oo = t & 127, nd = (t >> 7) & 1, ph = t >> 8;
    const float* src = u_s[nd] + ph * 64;
    const float* Wp = nw2 + (size_t)ph * 64 * HD + oo;
    float p = 0.f;
#pragma unroll
    for (int f4 = 0; f4 < 16; f4++) {
      float4 xv = *(const float4*)(src + f4 * 4);
      p = fmaf(xv.x, Wp[(f4 * 4 + 0) * HD], p);
      p = fmaf(xv.y, Wp[(f4 * 4 + 1) * HD], p);
      p = fmaf(xv.z, Wp[(f4 * 4 + 2) * HD], p);
      p = fmaf(xv.w, Wp[(f4 * 4 + 3) * HD], p);
    }
    red_s[t] = p;
  }
  __syncthreads();
  if (t < 256) {
    const int nd = t >> 7, oo = t & 127;
    h_out[(size_t)(i0 + nd) * HD + oo] = hi_s[nd][oo] + red_s[t] + red_s[t + 256] + nb2[oo];
  }
}

// ---------------- final heads (per node) ----------------
__global__ __launch_bounds__(256) void heads_kernel(
    const float* __restrict__ h, const float* __restrict__ pos,
    const float* __restrict__ fw1, const float* __restrict__ fb1,
    const float* __restrict__ fw2, const float* __restrict__ fb2,
    const float* __restrict__ cw1g, const float* __restrict__ cb1g,
    const float* __restrict__ cw2g, const float* __restrict__ cb2g,
    const float* __restrict__ sw, const float* __restrict__ sb,
    const float* __restrict__ iw,
    float* __restrict__ At, float* __restrict__ Bt,
    void* __restrict__ out, const int* __restrict__ flag) {
  __shared__ float hi_s[HD], v1[HD], red_s[256];
  const int i = blockIdx.x, t = threadIdx.x;
  const int fm = *flag;
  if (t < HD) hi_s[t] = h[(size_t)i * HD + t];
  __syncthreads();
  const int o = t & 127, ph = t >> 7;
  // forces MLP1
  {
    float p = 0.f;
#pragma unroll 4
    for (int f = ph * 64; f < ph * 64 + 64; f++) p = fmaf(hi_s[f], fw1[f * HD + o], p);
    red_s[t] = p;
  }
  __syncthreads();
  if (t < HD) v1[t] = tanhf(red_s[t] + red_s[t + 128] + fb1[t]);
  __syncthreads();
  if (t < 3) {
    float p = 0.f;
    for (int f = 0; f < HD; f++) p = fmaf(v1[f], fw2[f * 3 + t], p);
    stout(out, fm, OFF_F + (size_t)i * 3 + t, p + fb2[t]);
  }
  __syncthreads();
  // conformer MLP1
  {
    float p = 0.f;
#pragma unroll 4
    for (int f = ph * 64; f < ph * 64 + 64; f++) p = fmaf(hi_s[f], cw1g[f * HD + o], p);
    red_s[t] = p;
  }
  __syncthreads();
  if (t < HD) v1[t] = fmaxf(red_s[t] + red_s[t + 128] + cb1g[t], 0.f);
  __syncthreads();
  // conformer MLP2
  {
    const int oo = t & 63, pc = t >> 6;
    float p = 0.f;
#pragma unroll 4
    for (int f = pc * 32; f < pc * 32 + 32; f++) p = fmaf(v1[f], cw2g[f * 64 + oo], p);
    red_s[t] = p;
  }
  __syncthreads();
  if (t < 64)
    stout(out, fm, OFF_C + (size_t)i * 64 + t,
          red_s[t] + red_s[t + 64] + red_s[t + 128] + red_s[t + 192] + cb2g[t]);
  __syncthreads();
  // steric
  if (t < HD) red_s[t] = hi_s[t] * sw[t];
  __syncthreads();
  if (t == 0) {
    float p = 0.f;
    for (int f = 0; f < HD; f++) p += red_s[f];
    stout(out, fm, OFF_ST + (size_t)i, p + sb[0]);
  }
  __syncthreads();
  // interaction head per-node dots
  {
    const int g = t >> 5, l = t & 31;
    float p = 0.f;
    if (g < 6) {
      const int tt = g >> 1, half = g & 1;
#pragma unroll
      for (int r2 = 0; r2 < 4; r2++)
        p = fmaf(hi_s[l * 4 + r2], iw[tt * 258 + half * 128 + l * 4 + r2], p);
    }
    red_s[t] = p;
  }
  __syncthreads();
  if (t < 6) {
    float p = 0.f;
    for (int l = 0; l < 32; l++) p += red_s[t * 32 + l];
    const int tt = t >> 1;
    if ((t & 1) == 0) At[tt * NN + i] = p;
    else Bt[tt * NN + i] = p;
  }
  if (t < HD) stout(out, fm, OFF_H + (size_t)i * HD + t, hi_s[t]);
  if (t >= 128 && t < 131) stout(out, fm, OFF_POS + (size_t)i * 3 + (t - 128), pos[i * 3 + (t - 128)]);
}

// ---------------- interaction scores ----------------
__global__ void scores_kernel(const float* __restrict__ pos, const int* __restrict__ idx2,
                              const int* __restrict__ cnt2, const float* __restrict__ At,
                              const float* __restrict__ Bt, const float* __restrict__ iw,
                              const float* __restrict__ ib, void* __restrict__ out,
                              const int* __restrict__ flag) {
  int tid = blockIdx.x * 256 + threadIdx.x;
  if (tid >= 3 * NN * KI) return;
  const int fm = *flag;
  const int tt = tid / (NN * KI);
  const int r = tid % (NN * KI);
  const int n = r / KI;
  const int k = r % KI;
  float v = 0.f;
  if (k < cnt2[n]) {
    int j = idx2[n * KI + k];
    float dx = pos[n * 3 + 0] - pos[j * 3 + 0];
    float dy = pos[n * 3 + 1] - pos[j * 3 + 1];
    float dz = pos[n * 3 + 2] - pos[j * 3 + 2];
    float d2 = dx * dx + dy * dy + dz * dz;
    float dist = sqrtf(d2 + 1e-12f);
    float s = At[tt * NN + n] + Bt[tt * NN + j] + dist * iw[tt * 258 + 256] +
              (dist * 0.1f) * iw[tt * 258 + 257] + ib[tt];
    v = 1.f / (1.f + __expf(-s));
  }
  stout(out, fm, OFF_S + (size_t)tid, v);
}

extern "C" void kernel_launch(void* const* d_in, const int* in_sizes, int n_in,
                              void* d_out, int out_size, void* d_ws, size_t ws_size,
                              hipStream_t stream) {
  (void)in_sizes; (void)n_in; (void)out_size; (void)ws_size;

  float* wsf = (float*)d_ws;
  float* h_a = wsf + 0;             // 524288
  float* pos_a = wsf + 524288;      // 12288
  float* h_b = wsf + 536576;        // 524288
  float* pos_b = wsf + 1060864;     // 12288
  float* At = wsf + 1073152;        // 12288
  float* Bt = wsf + 1085440;        // 12288
  const int W0 = 1097728;

  static const int wcnt[23] = {197376, 768, 98304, 768, 98304, 768, 768,
                               196608, 768, 98304, 768, 16384, 128, 384, 3,
                               774, 3, 16384, 128, 8192, 64, 128, 1};
  int woff[23];
  {
    int o = W0;
    for (int k = 0; k < 23; k++) { woff[k] = o; o += wcnt[k]; }
  }
  const int IOFF = woff[22] + wcnt[22];
  int* ibase = (int*)d_ws;
  int* idx1 = ibase + IOFF;
  int* cnt1 = idx1 + NN * KE;
  int* idx2 = cnt1 + NN;
  int* cnt2 = idx2 + NN * KI;
  int* gstart = cnt2 + NN;
  int* flag = gstart + 33;
  // packed interleaved MFMA weight fragments, 16B-aligned
  int wboff = (int)((flag + 1) - ibase);
  wboff = (wboff + 3) & ~3;
  u16* WBP = (u16*)(ibase + wboff);

  const float* EW1 = wsf + woff[0];
  const float* EB1 = wsf + woff[1];
  const float* EB2 = wsf + woff[3];
  const float* CB1 = wsf + woff[5];
  const float* CW2 = wsf + woff[6];
  const float* NW1 = wsf + woff[7];
  const float* NB1 = wsf + woff[8];
  const float* NW2 = wsf + woff[9];
  const float* NB2 = wsf + woff[10];
  const float* FW1 = wsf + woff[11];
  const float* FB1 = wsf + woff[12];
  const float* FW2 = wsf + woff[13];
  const float* FB2 = wsf + woff[14];
  const float* IW = wsf + woff[15];
  const float* IB = wsf + woff[16];
  const float* CW1G = wsf + woff[17];
  const float* CB1G = wsf + woff[18];
  const float* CW2G = wsf + woff[19];
  const float* CB2G = wsf + woff[20];
  const float* SW = wsf + woff[21];
  const float* SB = wsf + woff[22];

  probe_dtype<<<1, 256, 0, stream>>>((const u16*)d_in[0], flag);

  CvtTable tab;
  tab.src[0] = d_in[0]; tab.dstoff[0] = 0;       tab.cnt[0] = NN * HD;
  tab.src[1] = d_in[1]; tab.dstoff[1] = 524288;  tab.cnt[1] = NN * 3;
  for (int k = 0; k < 23; k++) {
    tab.src[2 + k] = d_in[3 + k];
    tab.dstoff[2 + k] = woff[k];
    tab.cnt[2 + k] = wcnt[k];
  }
  {
    dim3 g((NN * HD + 255) / 256, 25, 1);
    convert_all<<<g, 256, 0, stream>>>(tab, wsf, flag);
  }
  pack_weights<<<(18 * 32768 + 255) / 256, 256, 0, stream>>>(
      wsf, woff[0], woff[2], woff[4], WBP);

  const int* batch = (const int*)d_in[2];
  graph_bounds<<<NN / 256, 256, 0, stream>>>(batch, gstart);

  const float cut2s[3] = {9.f, 36.f, 100.f};
  float *hin = h_a, *pin = pos_a, *hout = h_b, *pout = pos_b;
  for (int l = 0; l < 6; l++) {
    if ((l & 1) == 0)
      neigh_kernel<<<NN / 4, 256, 0, stream>>>(pin, batch, gstart, idx1, cnt1, KE, cut2s[l >> 1]);
    egnn_layer<<<NN / 2, 512, 0, stream>>>(
        hin, pin, hout, pout, idx1, cnt1,
        EW1 + (size_t)l * 257 * HD, EB1 + (size_t)l * HD,
        EB2 + (size_t)l * HD,
        CB1 + (size_t)l * HD, CW2 + (size_t)l * HD,
        NW1 + (size_t)l * 256 * HD, NB1 + (size_t)l * HD,
        NW2 + (size_t)l * HD * HD, NB2 + (size_t)l * HD,
        WBP + (size_t)l * 3 * 32768);
    float* th = hin; hin = hout; hout = th;
    float* tp = pin; pin = pout; pout = tp;
  }
  neigh_kernel<<<NN / 4, 256, 0, stream>>>(pin, batch, gstart, idx2, cnt2, KI, 100.f);
  heads_kernel<<<NN, 256, 0, stream>>>(hin, pin, FW1, FB1, FW2, FB2, CW1G, CB1G, CW2G, CB2G,
                                       SW, SB, IW, At, Bt, d_out, flag);
  scores_kernel<<<(3 * NN * KI + 255) / 256, 256, 0, stream>>>(
      pin, idx2, cnt2, At, Bt, IW, IB, d_out, flag);
}

// Round 6
// 860.450 us; speedup vs baseline: 1.3614x; 1.0078x over previous
//
#include <hip/hip_runtime.h>
#include <hip/hip_bf16.h>

#define NN 4096
#define HD 128
#define KE 32
#define KI 20
#define XLD 132   // X LDS row stride in u32 (16B-aligned rows)
#define PLOF 68   // lo-plane column offset within a row (16B-aligned)

// output element offsets
#define OFF_H   0
#define OFF_POS 524288
#define OFF_F   536576
#define OFF_S   548864
#define OFF_C   794624
#define OFF_ST  1056768

typedef unsigned short u16;
typedef unsigned int u32;
typedef unsigned long long u64;
typedef __attribute__((ext_vector_type(8))) short bf16x8;   // 8 bf16 (4 VGPR)
typedef __attribute__((ext_vector_type(4))) float f32x4;

__device__ __forceinline__ float b2f(u16 u) {
  union { u32 i; float f; } c; c.i = ((u32)u) << 16; return c.f;
}
__device__ __forceinline__ float silu_f(float x) { return x / (1.f + __expf(-x)); }
__device__ __forceinline__ void stout(void* out, int fp32m, size_t i, float v) {
  if (fp32m) ((float*)out)[i] = v;
  else ((__hip_bfloat16*)out)[i] = __float2bfloat16(v);
}
// RNE float->bf16 bits (reference path, used in pack_weights)
__device__ __forceinline__ u32 f2b(float f) {
  u32 u = __float_as_uint(f);
  return (u + 0x7fffu + ((u >> 16) & 1u)) >> 16;
}
// hi/lo split of two adjacent values -> plane words (H=[b:a] hi, L=[b:a] lo)
__device__ __forceinline__ void packplane(float a, float b, u32& H, u32& L) {
  asm("v_cvt_pk_bf16_f32 %0, %1, %2" : "=v"(H) : "v"(a), "v"(b));
  float hfa = __uint_as_float(H << 16);
  float hfb = __uint_as_float(H & 0xffff0000u);
  asm("v_cvt_pk_bf16_f32 %0, %1, %2" : "=v"(L) : "v"(a - hfa), "v"(b - hfb));
}

// ---------------- dtype probe ----------------
__global__ void probe_dtype(const u16* __restrict__ h, int* __restrict__ flag) {
  if (threadIdx.x == 0) atomicExch(flag, 0);
  __syncthreads();
  int bad = 0;
  for (int i = threadIdx.x; i < 8192; i += 256) {
    float v = b2f(h[i]);
    if (!(v > -1000.f && v < 1000.f)) bad = 1;
  }
  if (bad) atomicOr(flag, 1);
}

// ---------------- convert all float tensors -> fp32 workspace ----------------
struct CvtTable {
  const void* src[25];
  int dstoff[25];
  int cnt[25];
};

__global__ void convert_all(CvtTable tab, float* __restrict__ wsf, const int* __restrict__ flag) {
  const int seg = blockIdx.y;
  const int i = blockIdx.x * 256 + threadIdx.x;
  if (i >= tab.cnt[seg]) return;
  float v;
  if (*flag) v = ((const float*)tab.src[seg])[i];
  else       v = b2f(((const u16*)tab.src[seg])[i]);
  wsf[tab.dstoff[seg] + i] = v;
}

// ------- pack stage weights: interleaved hi/lo MFMA fragments -------
// Layout: [mat 18][kt 4][ot 8][lane 64][16 u16] where [0..8)=hi j, [8..16)=lo j.
// Used as the A-operand of OUT^T = W^T X^T: lane l holds A[row=o=l&15]
// [k=f=(l>>4)*8+j] -- identical data permutation as the original B-frag.
__global__ void pack_weights(const float* __restrict__ wsf, int offEW1, int offEW2, int offCW1,
                             u16* __restrict__ WBP) {
  int tid = blockIdx.x * 256 + threadIdx.x;
  if (tid >= 18 * 32768) return;
  int m = tid >> 15;
  int rix = tid & 32767;
  int layer = m / 3, s = m % 3;
  const float* src;
  if (s == 0)      src = wsf + offEW1 + (size_t)layer * 257 * HD + 128 * HD;
  else if (s == 1) src = wsf + offEW2 + (size_t)layer * HD * HD;
  else             src = wsf + offCW1 + (size_t)layer * HD * HD;
  int jh = rix & 15, lane = (rix >> 4) & 63, ot = (rix >> 10) & 7, kt = rix >> 13;
  int j = jh & 7;
  int f = kt * 32 + (lane >> 4) * 8 + j;
  int o = ot * 16 + (lane & 15);
  float v = src[f * HD + o];
  u32 hb = f2b(v);
  float hf = __uint_as_float(hb << 16);
  u32 lb = f2b(v - hf);
  WBP[tid] = (jh < 8) ? (u16)hb : (u16)lb;
}

// ---------------- graph boundaries from sorted batch ----------------
__global__ void graph_bounds(const int* __restrict__ batch, int* __restrict__ gstart) {
  int n = blockIdx.x * 256 + threadIdx.x;
  if (n >= NN) return;
  int v = batch[n];
  int pv = (n == 0) ? -1 : batch[n - 1];
  for (int b = pv + 1; b <= v; b++) gstart[b] = n;
  if (n == NN - 1) for (int b = v + 1; b <= 32; b++) gstart[b] = NN;
}

// ---------------- exact k-NN within cutoff (one wave per node) ----------------
__global__ __launch_bounds__(256) void neigh_kernel(
    const float* __restrict__ pos, const int* __restrict__ batch,
    const int* __restrict__ gstart, int* __restrict__ idx, int* __restrict__ cnt,
    int Ksel, float cut2) {
  const int lane = threadIdx.x & 63;
  const int i = blockIdx.x * 4 + (threadIdx.x >> 6);
  const int b = batch[i];
  const int gs = gstart[b];
  const int ge = gstart[b + 1];
  const int span = ge - gs;
  const float px = pos[i * 3 + 0], py = pos[i * 3 + 1], pz = pos[i * 3 + 2];
  u64 key[16];
#pragma unroll
  for (int tq = 0; tq < 16; tq++) {
    u64 k64 = ~0ull;
    if (tq * 64 < span) {
      int j = gs + tq * 64 + lane;
      if (j < ge && j != i) {
        float dx = px - pos[j * 3 + 0];
        float dy = py - pos[j * 3 + 1];
        float dz = pz - pos[j * 3 + 2];
        float d2 = dx * dx + dy * dy + dz * dz;
        if (d2 <= cut2) k64 = (((u64)__float_as_uint(d2)) << 32) | (u32)j;
      }
    }
    key[tq] = k64;
  }
  u64 thresh = 0;
  int myidx = i;
  int mycnt = 0;
  for (int s = 0; s < Ksel; s++) {
    u64 m = ~0ull;
#pragma unroll
    for (int tq = 0; tq < 16; tq++) {
      if (tq * 64 < span) {
        u64 kk = key[tq];
        if (kk >= thresh && kk < m) m = kk;
      }
    }
    for (int off = 32; off > 0; off >>= 1) {
      u64 o = __shfl_down(m, (unsigned)off, 64);
      if (o < m) m = o;
    }
    m = __shfl(m, 0, 64);
    if (m != ~0ull) {
      if (lane == s) myidx = (int)(m & 0xffffffffu);
      mycnt++;
      thresh = m + 1;
    } else break;
  }
  if (lane < Ksel) idx[i * Ksel + lane] = myidx;
  if (lane == 0) cnt[i] = mycnt;
}

// Swapped-operand 3-term split-bf16 MFMA stage: acc[Et] = (X W)^T tile for
// e-tile Et, o-tile w. A = packed weights (W^T), B = plane X rows (X^T).
// D mapping: col = e-in-tile = lane&15, row = o-in-tile = (lane>>4)*4+reg.
// Dead e-tiles (beyond ceil(cn/16)) skipped via wave-uniform guards.
__device__ __forceinline__ void mfma_stageS(const u32* xp_, const u16* __restrict__ WP,
                                            int w, int lane, int nt0, int nt1,
                                            f32x4 acc[4]) {
  const int l16 = lane & 15, q = lane >> 4;
  f32x4 z = {0.f, 0.f, 0.f, 0.f};
  acc[0] = z; acc[1] = z; acc[2] = z; acc[3] = z;
#pragma unroll
  for (int kt = 0; kt < 4; kt++) {
    const u16* wb = WP + (size_t)((kt * 8 + w) * 64 + lane) * 16;
    bf16x8 wh = *(const bf16x8*)(wb);
    bf16x8 wl = *(const bf16x8*)(wb + 8);
#pragma unroll
    for (int Et = 0; Et < 4; Et++) {
      if ((Et < 2) ? (Et < nt0) : (Et - 2 < nt1)) {
        const u32* xr = xp_ + (Et * 16 + l16) * XLD + kt * 16 + q * 4;
        bf16x8 xh = *(const bf16x8*)(xr);
        bf16x8 xl = *(const bf16x8*)(xr + PLOF);
        // same 3-term order as before (terms transposed): bit-identical chains
        acc[Et] = __builtin_amdgcn_mfma_f32_16x16x32_bf16(wh, xl, acc[Et], 0, 0, 0);
        acc[Et] = __builtin_amdgcn_mfma_f32_16x16x32_bf16(wl, xh, acc[Et], 0, 0, 0);
        acc[Et] = __builtin_amdgcn_mfma_f32_16x16x32_bf16(wh, xh, acc[Et], 0, 0, 0);
      }
    }
  }
}

// ---------------- one EGNN layer, one block per 2 nodes ----------------
__global__ __launch_bounds__(512, 4) void egnn_layer(
    const float* __restrict__ h_in, const float* __restrict__ pos_in,
    float* __restrict__ h_out, float* __restrict__ pos_out,
    const int* __restrict__ idx, const int* __restrict__ cnt,
    const float* __restrict__ ew1, const float* __restrict__ eb1,
    const float* __restrict__ eb2,
    const float* __restrict__ cb1, const float* __restrict__ cw2,
    const float* __restrict__ nw1, const float* __restrict__ nb1,
    const float* __restrict__ nw2, const float* __restrict__ nb2,
    const u16* __restrict__ wbp) {
  __shared__ __align__(16) u32 xp[64 * XLD];  // X planes: hi [0,64), lo [68,132)
  __shared__ float hi_s[2][HD], hpart_s[2][HD], msum_s[2][HD], u_s[2][HD];
  __shared__ float red_s[512];
  __shared__ float ce_red[64][8];
  __shared__ float rel_s[3][64], d2_s[64], mf_s[64], ce_s[64];
  __shared__ int idx_s[64], cn_s[2];

  const int t = threadIdx.x;
  const int i0 = blockIdx.x * 2;
  const int lane = t & 63;
  const int w = __builtin_amdgcn_readfirstlane(t >> 6);  // wave's o-tile, 0..7
  const int l16 = lane & 15, q = lane >> 4;

  if (t < 64) idx_s[t] = idx[(size_t)(i0 + (t >> 5)) * KE + (t & 31)];
  else if (t < 66) cn_s[t - 64] = cnt[i0 + (t - 64)];
  if (t >= 256) {
    const int nt = t - 256;
    hi_s[nt >> 7][nt & 127] = h_in[(size_t)(i0 + (nt >> 7)) * HD + (nt & 127)];
  }
  __syncthreads();

  const int nt0 = __builtin_amdgcn_readfirstlane((cn_s[0] + 15) >> 4);  // live e-tiles node0
  const int nt1 = __builtin_amdgcn_readfirstlane((cn_s[1] + 15) >> 4);  // live e-tiles node1

  if (t < 64) {
    const int nd = t >> 5, ic = i0 + nd;
    const int j = idx_s[t];
    const float rx = pos_in[ic * 3 + 0] - pos_in[j * 3 + 0];
    const float ry = pos_in[ic * 3 + 1] - pos_in[j * 3 + 1];
    const float rz = pos_in[ic * 3 + 2] - pos_in[j * 3 + 2];
    rel_s[0][t] = rx; rel_s[1][t] = ry; rel_s[2][t] = rz;
    d2_s[t] = rx * rx + ry * ry + rz * rz;
    mf_s[t] = ((t & 31) < cn_s[nd]) ? 1.0f : 0.0f;
  }
  // gather hj -> hi/lo planes; 4x b128 writes (bank-optimal); dead tiles skipped
  {
    const int ge_ = t & 63;
    const int myEt = ge_ >> 4;
    const bool glive = (myEt < 2) ? (myEt < nt0) : (myEt - 2 < nt1);
    if (glive) {
      const int j = idx_s[ge_];
      const int f0 = (t >> 6) * 16;
      const float4* src = (const float4*)(h_in + (size_t)j * HD + f0);
      float4 v0 = src[0], v1 = src[1], v2 = src[2], v3 = src[3];
      u32 H0, L0, H1, L1, H2, L2, H3, L3, H4, L4, H5, L5, H6, L6, H7, L7;
      packplane(v0.x, v0.y, H0, L0); packplane(v0.z, v0.w, H1, L1);
      packplane(v1.x, v1.y, H2, L2); packplane(v1.z, v1.w, H3, L3);
      packplane(v2.x, v2.y, H4, L4); packplane(v2.z, v2.w, H5, L5);
      packplane(v3.x, v3.y, H6, L6); packplane(v3.z, v3.w, H7, L7);
      u32* dh = xp + ge_ * XLD + (f0 >> 1);
      uint4 a; a.x = H0; a.y = H1; a.z = H2; a.w = H3;
      uint4 b; b.x = H4; b.y = H5; b.z = H6; b.w = H7;
      uint4 c; c.x = L0; c.y = L1; c.z = L2; c.w = L3;
      uint4 d; d.x = L4; d.y = L5; d.z = L6; d.w = L7;
      *(uint4*)(dh) = a;            *(uint4*)(dh + 4) = b;
      *(uint4*)(dh + PLOF) = c;     *(uint4*)(dh + PLOF + 4) = d;
    }
  }
  // hpart[nd][o] = hi . ew1[0:128, o]
  {
    const int oo = t & 127, nd = (t >> 7) & 1, hf = t >> 8;
    const float* hsrc = hi_s[nd];
    float hp = 0.f;
#pragma unroll
    for (int f4 = hf * 16; f4 < hf * 16 + 16; f4++) {
      float4 xv = *(const float4*)(hsrc + f4 * 4);
      hp = fmaf(xv.x, ew1[(f4 * 4 + 0) * HD + oo], hp);
      hp = fmaf(xv.y, ew1[(f4 * 4 + 1) * HD + oo], hp);
      hp = fmaf(xv.z, ew1[(f4 * 4 + 2) * HD + oo], hp);
      hp = fmaf(xv.w, ew1[(f4 * 4 + 3) * HD + oo], hp);
    }
    red_s[t] = hp;
  }
  __syncthreads();
  if (t < 256) hpart_s[t >> 7][t & 127] = red_s[t] + red_s[t + 256] + eb1[t & 127];
  __syncthreads();

  // ---- stage B: m1 = silu(hpart + hj @ ew1[128:256] + d2*ew1[256]) ----
  {
    f32x4 acc[4];
    mfma_stageS(xp, wbp, w, lane, nt0, nt1, acc);
    __syncthreads();  // all plane reads done before in-place overwrite
    const float4 w24 = *(const float4*)(ew1 + 256 * HD + w * 16 + q * 4);
#pragma unroll
    for (int Et = 0; Et < 4; Et++) {
      if ((Et < 2) ? (Et < nt0) : (Et - 2 < nt1)) {
        const int ee = Et * 16 + l16;
        const float d2e = d2_s[ee];
        const float4 hp4 = *(const float4*)(&hpart_s[Et >> 1][w * 16 + q * 4]);
        float s0 = silu_f(acc[Et][0] + hp4.x + d2e * w24.x);
        float s1 = silu_f(acc[Et][1] + hp4.y + d2e * w24.y);
        float s2 = silu_f(acc[Et][2] + hp4.z + d2e * w24.z);
        float s3 = silu_f(acc[Et][3] + hp4.w + d2e * w24.w);
        u32 H0, L0, H1, L1;
        packplane(s0, s1, H0, L0);
        packplane(s2, s3, H1, L1);
        u32* dst = xp + ee * XLD + w * 8 + q * 2;
        uint2 hh; hh.x = H0; hh.y = H1;
        uint2 ll; ll.x = L0; ll.y = L1;
        *(uint2*)(dst) = hh;
        *(uint2*)(dst + PLOF) = ll;
      }
    }
  }
  __syncthreads();

  // ---- stage C: m2 = mask ? silu(m1 @ ew2 + eb2) : 0 ; msum per node ----
  {
    f32x4 acc[4];
    mfma_stageS(xp, wbp + 32768, w, lane, nt0, nt1, acc);
    __syncthreads();  // all reads done before in-place overwrite
    const float4 eb4 = *(const float4*)(eb2 + w * 16 + q * 4);
    float ms0x = 0.f, ms0y = 0.f, ms0z = 0.f, ms0w = 0.f;
    float ms1x = 0.f, ms1y = 0.f, ms1z = 0.f, ms1w = 0.f;
#pragma unroll
    for (int Et = 0; Et < 4; Et++) {
      if ((Et < 2) ? (Et < nt0) : (Et - 2 < nt1)) {
        const int ee = Et * 16 + l16;
        const float mfv = mf_s[ee];
        float m0 = (mfv != 0.f) ? silu_f(acc[Et][0] + eb4.x) : 0.f;
        float m1 = (mfv != 0.f) ? silu_f(acc[Et][1] + eb4.y) : 0.f;
        float m2 = (mfv != 0.f) ? silu_f(acc[Et][2] + eb4.z) : 0.f;
        float m3 = (mfv != 0.f) ? silu_f(acc[Et][3] + eb4.w) : 0.f;
        if (Et < 2) { ms0x += m0; ms0y += m1; ms0z += m2; ms0w += m3; }
        else        { ms1x += m0; ms1y += m1; ms1z += m2; ms1w += m3; }
        u32 H0, L0, H1, L1;
        packplane(m0, m1, H0, L0);
        packplane(m2, m3, H1, L1);
        u32* dst = xp + ee * XLD + w * 8 + q * 2;
        uint2 hh; hh.x = H0; hh.y = H1;
        uint2 ll; ll.x = L0; ll.y = L1;
        *(uint2*)(dst) = hh;
        *(uint2*)(dst + PLOF) = ll;
      }
    }
#define RED16(v) v += __shfl_xor(v, 1); v += __shfl_xor(v, 2); \
                 v += __shfl_xor(v, 4); v += __shfl_xor(v, 8);
    RED16(ms0x) RED16(ms0y) RED16(ms0z) RED16(ms0w)
    RED16(ms1x) RED16(ms1y) RED16(ms1z) RED16(ms1w)
#undef RED16
    if (l16 == 0) {
      float4 a; a.x = ms0x; a.y = ms0y; a.z = ms0z; a.w = ms0w;
      float4 b; b.x = ms1x; b.y = ms1y; b.z = ms1z; b.w = ms1w;
      *(float4*)(&msum_s[0][w * 16 + q * 4]) = a;
      *(float4*)(&msum_s[1][w * 16 + q * 4]) = b;
    }
  }
  __syncthreads();

  // ---- stage D: c1 = silu(m2 @ cw1 + cb1); fold cw2 dot; per-e partials ----
  {
    f32x4 acc[4];
    mfma_stageS(xp, wbp + 65536, w, lane, nt0, nt1, acc);
    const float4 cb4 = *(const float4*)(cb1 + w * 16 + q * 4);
    const float4 cw4 = *(const float4*)(cw2 + w * 16 + q * 4);
#pragma unroll
    for (int Et = 0; Et < 4; Et++) {
      if ((Et < 2) ? (Et < nt0) : (Et - 2 < nt1)) {
        float p = silu_f(acc[Et][0] + cb4.x) * cw4.x;
        p = fmaf(silu_f(acc[Et][1] + cb4.y), cw4.y, p);
        p = fmaf(silu_f(acc[Et][2] + cb4.z), cw4.z, p);
        p = fmaf(silu_f(acc[Et][3] + cb4.w), cw4.w, p);
        p += __shfl_xor(p, 16);
        p += __shfl_xor(p, 32);
        if (lane < 16) ce_red[Et * 16 + lane][w] = p;
      }
    }
  }
  __syncthreads();
  if (t < 64) {
    float c = 0.f;
#pragma unroll
    for (int wv = 0; wv < 8; wv++) c += ce_red[t][wv];
    ce_s[t] = (mf_s[t] != 0.f) ? c : 0.f;
  }
  __syncthreads();
  // ---- pos update ----
  if (t < 6) {
    const int nd = t / 3, ax = t - nd * 3, ic = i0 + nd;
    float s = 0.f;
#pragma unroll
    for (int k = 0; k < 32; k++) s = fmaf(rel_s[ax][nd * 32 + k], ce_s[nd * 32 + k], s);
    const float cntf = fmaxf((float)cn_s[nd], 1.f);
    pos_out[ic * 3 + ax] = pos_in[ic * 3 + ax] + s / cntf;
  }
  // ---- node MLP1 ----
  {
    const int oo = t & 127, nd = (t >> 7) & 1, ph = t >> 8;
    const float* src = ph ? msum_s[nd] : hi_s[nd];
    const float* Wp = nw1 + (size_t)ph * 128 * HD + oo;
    float p = 0.f;
#pragma unroll
    for (int f4 = 0; f4 < 32; f4++) {
      float4 xv = *(const float4*)(src + f4 * 4);
      p = fmaf(xv.x, Wp[(f4 * 4 + 0) * HD], p);
      p = fmaf(xv.y, Wp[(f4 * 4 + 1) * HD], p);
      p = fmaf(xv.z, Wp[(f4 * 4 + 2) * HD], p);
      p = fmaf(xv.w, Wp[(f4 * 4 + 3) * HD], p);
    }
    red_s[t] = p;
  }
  __syncthreads();
  if (t < 256) u_s[t >> 7][t & 127] = silu_f(red_s[t] + red_s[t + 256] + nb1[t & 127]);
  __syncthreads();
  // ---- node MLP2 + residual ----
  {
    const int oo = t & 127, nd = (t >> 7) & 1, ph = t >> 8;
    const float* src = u_s[nd] + ph * 64;
    const float* Wp = nw2 + (size_t)ph * 64 * HD + oo;
    float p = 0.f;
#pragma unroll
    for (int f4 = 0; f4 < 16; f4++) {
      float4 xv = *(const float4*)(src + f4 * 4);
      p = fmaf(xv.x, Wp[(f4 * 4 + 0) * HD], p);
      p = fmaf(xv.y, Wp[(f4 * 4 + 1) * HD], p);
      p = fmaf(xv.z, Wp[(f4 * 4 + 2) * HD], p);
      p = fmaf(xv.w, Wp[(f4 * 4 + 3) * HD], p);
    }
    red_s[t] = p;
  }
  __syncthreads();
  if (t < 256) {
    const int nd = t >> 7, oo = t & 127;
    h_out[(size_t)(i0 + nd) * HD + oo] = hi_s[nd][oo] + red_s[t] + red_s[t + 256] + nb2[oo];
  }
}

// ---------------- final heads (per node) ----------------
__global__ __launch_bounds__(256) void heads_kernel(
    const float* __restrict__ h, const float* __restrict__ pos,
    const float* __restrict__ fw1, const float* __restrict__ fb1,
    const float* __restrict__ fw2, const float* __restrict__ fb2,
    const float* __restrict__ cw1g, const float* __restrict__ cb1g,
    const float* __restrict__ cw2g, const float* __restrict__ cb2g,
    const float* __restrict__ sw, const float* __restrict__ sb,
    const float* __restrict__ iw,
    float* __restrict__ At, float* __restrict__ Bt,
    void* __restrict__ out, const int* __restrict__ flag) {
  __shared__ float hi_s[HD], v1[HD], red_s[256];
  const int i = blockIdx.x, t = threadIdx.x;
  const int fm = *flag;
  if (t < HD) hi_s[t] = h[(size_t)i * HD + t];
  __syncthreads();
  const int o = t & 127, ph = t >> 7;
  // forces MLP1
  {
    float p = 0.f;
#pragma unroll 4
    for (int f = ph * 64; f < ph * 64 + 64; f++) p = fmaf(hi_s[f], fw1[f * HD + o], p);
    red_s[t] = p;
  }
  __syncthreads();
  if (t < HD) v1[t] = tanhf(red_s[t] + red_s[t + 128] + fb1[t]);
  __syncthreads();
  if (t < 3) {
    float p = 0.f;
    for (int f = 0; f < HD; f++) p = fmaf(v1[f], fw2[f * 3 + t], p);
    stout(out, fm, OFF_F + (size_t)i * 3 + t, p + fb2[t]);
  }
  __syncthreads();
  // conformer MLP1
  {
    float p = 0.f;
#pragma unroll 4
    for (int f = ph * 64; f < ph * 64 + 64; f++) p = fmaf(hi_s[f], cw1g[f * HD + o], p);
    red_s[t] = p;
  }
  __syncthreads();
  if (t < HD) v1[t] = fmaxf(red_s[t] + red_s[t + 128] + cb1g[t], 0.f);
  __syncthreads();
  // conformer MLP2
  {
    const int oo = t & 63, pc = t >> 6;
    float p = 0.f;
#pragma unroll 4
    for (int f = pc * 32; f < pc * 32 + 32; f++) p = fmaf(v1[f], cw2g[f * 64 + oo], p);
    red_s[t] = p;
  }
  __syncthreads();
  if (t < 64)
    stout(out, fm, OFF_C + (size_t)i * 64 + t,
          red_s[t] + red_s[t + 64] + red_s[t + 128] + red_s[t + 192] + cb2g[t]);
  __syncthreads();
  // steric
  if (t < HD) red_s[t] = hi_s[t] * sw[t];
  __syncthreads();
  if (t == 0) {
    float p = 0.f;
    for (int f = 0; f < HD; f++) p += red_s[f];
    stout(out, fm, OFF_ST + (size_t)i, p + sb[0]);
  }
  __syncthreads();
  // interaction head per-node dots
  {
    const int g = t >> 5, l = t & 31;
    float p = 0.f;
    if (g < 6) {
      const int tt = g >> 1, half = g & 1;
#pragma unroll
      for (int r2 = 0; r2 < 4; r2++)
        p = fmaf(hi_s[l * 4 + r2], iw[tt * 258 + half * 128 + l * 4 + r2], p);
    }
    red_s[t] = p;
  }
  __syncthreads();
  if (t < 6) {
    float p = 0.f;
    for (int l = 0; l < 32; l++) p += red_s[t * 32 + l];
    const int tt = t >> 1;
    if ((t & 1) == 0) At[tt * NN + i] = p;
    else Bt[tt * NN + i] = p;
  }
  if (t < HD) stout(out, fm, OFF_H + (size_t)i * HD + t, hi_s[t]);
  if (t >= 128 && t < 131) stout(out, fm, OFF_POS + (size_t)i * 3 + (t - 128), pos[i * 3 + (t - 128)]);
}

// ---------------- interaction scores ----------------
__global__ void scores_kernel(const float* __restrict__ pos, const int* __restrict__ idx2,
                              const int* __restrict__ cnt2, const float* __restrict__ At,
                              const float* __restrict__ Bt, const float* __restrict__ iw,
                              const float* __restrict__ ib, void* __restrict__ out,
                              const int* __restrict__ flag) {
  int tid = blockIdx.x * 256 + threadIdx.x;
  if (tid >= 3 * NN * KI) return;
  const int fm = *flag;
  const int tt = tid / (NN * KI);
  const int r = tid % (NN * KI);
  const int n = r / KI;
  const int k = r % KI;
  float v = 0.f;
  if (k < cnt2[n]) {
    int j = idx2[n * KI + k];
    float dx = pos[n * 3 + 0] - pos[j * 3 + 0];
    float dy = pos[n * 3 + 1] - pos[j * 3 + 1];
    float dz = pos[n * 3 + 2] - pos[j * 3 + 2];
    float d2 = dx * dx + dy * dy + dz * dz;
    float dist = sqrtf(d2 + 1e-12f);
    float s = At[tt * NN + n] + Bt[tt * NN + j] + dist * iw[tt * 258 + 256] +
              (dist * 0.1f) * iw[tt * 258 + 257] + ib[tt];
    v = 1.f / (1.f + __expf(-s));
  }
  stout(out, fm, OFF_S + (size_t)tid, v);
}

extern "C" void kernel_launch(void* const* d_in, const int* in_sizes, int n_in,
                              void* d_out, int out_size, void* d_ws, size_t ws_size,
                              hipStream_t stream) {
  (void)in_sizes; (void)n_in; (void)out_size; (void)ws_size;

  float* wsf = (float*)d_ws;
  float* h_a = wsf + 0;             // 524288
  float* pos_a = wsf + 524288;      // 12288
  float* h_b = wsf + 536576;        // 524288
  float* pos_b = wsf + 1060864;     // 12288
  float* At = wsf + 1073152;        // 12288
  float* Bt = wsf + 1085440;        // 12288
  const int W0 = 1097728;

  static const int wcnt[23] = {197376, 768, 98304, 768, 98304, 768, 768,
                               196608, 768, 98304, 768, 16384, 128, 384, 3,
                               774, 3, 16384, 128, 8192, 64, 128, 1};
  int woff[23];
  {
    int o = W0;
    for (int k = 0; k < 23; k++) { woff[k] = o; o += wcnt[k]; }
  }
  const int IOFF = woff[22] + wcnt[22];
  int* ibase = (int*)d_ws;
  int* idx1 = ibase + IOFF;
  int* cnt1 = idx1 + NN * KE;
  int* idx2 = cnt1 + NN;
  int* cnt2 = idx2 + NN * KI;
  int* gstart = cnt2 + NN;
  int* flag = gstart + 33;
  // packed interleaved MFMA weight fragments, 16B-aligned
  int wboff = (int)((flag + 1) - ibase);
  wboff = (wboff + 3) & ~3;
  u16* WBP = (u16*)(ibase + wboff);

  const float* EW1 = wsf + woff[0];
  const float* EB1 = wsf + woff[1];
  const float* EB2 = wsf + woff[3];
  const float* CB1 = wsf + woff[5];
  const float* CW2 = wsf + woff[6];
  const float* NW1 = wsf + woff[7];
  const float* NB1 = wsf + woff[8];
  const float* NW2 = wsf + woff[9];
  const float* NB2 = wsf + woff[10];
  const float* FW1 = wsf + woff[11];
  const float* FB1 = wsf + woff[12];
  const float* FW2 = wsf + woff[13];
  const float* FB2 = wsf + woff[14];
  const float* IW = wsf + woff[15];
  const float* IB = wsf + woff[16];
  const float* CW1G = wsf + woff[17];
  const float* CB1G = wsf + woff[18];
  const float* CW2G = wsf + woff[19];
  const float* CB2G = wsf + woff[20];
  const float* SW = wsf + woff[21];
  const float* SB = wsf + woff[22];

  probe_dtype<<<1, 256, 0, stream>>>((const u16*)d_in[0], flag);

  CvtTable tab;
  tab.src[0] = d_in[0]; tab.dstoff[0] = 0;       tab.cnt[0] = NN * HD;
  tab.src[1] = d_in[1]; tab.dstoff[1] = 524288;  tab.cnt[1] = NN * 3;
  for (int k = 0; k < 23; k++) {
    tab.src[2 + k] = d_in[3 + k];
    tab.dstoff[2 + k] = woff[k];
    tab.cnt[2 + k] = wcnt[k];
  }
  {
    dim3 g((NN * HD + 255) / 256, 25, 1);
    convert_all<<<g, 256, 0, stream>>>(tab, wsf, flag);
  }
  pack_weights<<<(18 * 32768 + 255) / 256, 256, 0, stream>>>(
      wsf, woff[0], woff[2], woff[4], WBP);

  const int* batch = (const int*)d_in[2];
  graph_bounds<<<NN / 256, 256, 0, stream>>>(batch, gstart);

  const float cut2s[3] = {9.f, 36.f, 100.f};
  float *hin = h_a, *pin = pos_a, *hout = h_b, *pout = pos_b;
  for (int l = 0; l < 6; l++) {
    if ((l & 1) == 0)
      neigh_kernel<<<NN / 4, 256, 0, stream>>>(pin, batch, gstart, idx1, cnt1, KE, cut2s[l >> 1]);
    egnn_layer<<<NN / 2, 512, 0, stream>>>(
        hin, pin, hout, pout, idx1, cnt1,
        EW1 + (size_t)l * 257 * HD, EB1 + (size_t)l * HD,
        EB2 + (size_t)l * HD,
        CB1 + (size_t)l * HD, CW2 + (size_t)l * HD,
        NW1 + (size_t)l * 256 * HD, NB1 + (size_t)l * HD,
        NW2 + (size_t)l * HD * HD, NB2 + (size_t)l * HD,
        WBP + (size_t)l * 3 * 32768);
    float* th = hin; hin = hout; hout = th;
    float* tp = pin; pin = pout; pout = tp;
  }
  neigh_kernel<<<NN / 4, 256, 0, stream>>>(pin, batch, gstart, idx2, cnt2, KI, 100.f);
  heads_kernel<<<NN, 256, 0, stream>>>(hin, pin, FW1, FB1, FW2, FB2, CW1G, CB1G, CW2G, CB2G,
                                       SW, SB, IW, At, Bt, d_out, flag);
  scores_kernel<<<(3 * NN * KI + 255) / 256, 256, 0, stream>>>(
      pin, idx2, cnt2, At, Bt, IW, IB, d_out, flag);
}